// Round 2
// baseline (208.852 us; speedup 1.0000x reference)
//
#include <hip/hip_runtime.h>
#include <math.h>

// ---------------------------------------------------------------------------
// SlidingWindowGQA: x[2,2048,2048] f32, wq[2048,2048], wk/wv[2048,512], wo[2048,2048]
// out f32 [2,2048,2048].  B=2 S=2048 H=16 KVH=4 D=128 WINDOW=512.
// R2: deep-pipelined GEMM (BK=32, 4-buf LDS ring, counted vmcnt, 1 barrier/tile,
//     conflict-free permuted-unit LDS layout, setprio), V-transpose fused into
//     QKV epilogue, merged convT/rope launches. Attention unchanged.
// ---------------------------------------------------------------------------

typedef unsigned short u16;
typedef __attribute__((ext_vector_type(4))) float f32x4;
typedef __attribute__((ext_vector_type(8))) __bf16 bf16x8;
typedef __attribute__((ext_vector_type(4))) __bf16 bf16x4;
typedef __attribute__((ext_vector_type(4))) short s16x4;
typedef __attribute__((ext_vector_type(8))) unsigned short u16x8;
typedef __attribute__((ext_vector_type(4))) unsigned short u16x4;

#define DEV static __device__ __forceinline__
#define WAITV(n) asm volatile("s_waitcnt vmcnt(" #n ")" ::: "memory")

DEV float bf2f(u16 h) {
    union { unsigned int i; float f; } x;
    x.i = ((unsigned int)h) << 16;
    return x.f;
}
DEV u16 f2bf(float f) {
    union { float f; unsigned int i; } x;
    x.f = f;
    unsigned int u = x.i;
    return (u16)((u + 0x7FFFu + ((u >> 16) & 1u)) >> 16);
}

DEV f32x4 mfma32(bf16x8 a, bf16x8 b, f32x4 c) {
    return __builtin_amdgcn_mfma_f32_16x16x32_bf16(a, b, c, 0, 0, 0);
}
DEV f32x4 mfma16(bf16x4 a, bf16x4 b, f32x4 c) {
#if __has_builtin(__builtin_amdgcn_mfma_f32_16x16x16_bf16)
    return __builtin_amdgcn_mfma_f32_16x16x16_bf16(a, b, c, 0, 0, 0);
#else
    union { bf16x4 v; s16x4 s; } ua, ub;
    ua.v = a; ub.v = b;
    return __builtin_amdgcn_mfma_f32_16x16x16bf16_1k(ua.s, ub.s, c, 0, 0, 0);
#endif
}

DEV void gload_lds16(const void* g, void* lds) {
    __builtin_amdgcn_global_load_lds(
        (const __attribute__((address_space(1))) unsigned int*)g,
        (__attribute__((address_space(3))) unsigned int*)lds, 16, 0, 0);
}

// ---------------------------------------------------------------------------
// cos/sin table: ct/st[s][d], s in [0,2048), d in [0,64)
__global__ __launch_bounds__(256) void sincos_kernel(float* ct, float* st) {
    int idx = blockIdx.x * 256 + threadIdx.x;      // 131072 total
    int s = idx >> 6, d = idx & 63;
    float inv = exp2f(-(float)d * (13.287712379549449f / 64.f));
    float a = (float)s * inv;
    float sv, cv;
    sincosf(a, &sv, &cv);
    ct[idx] = cv;
    st[idx] = sv;
}

// f32 -> bf16 straight convert, 4 elems/thread
__global__ __launch_bounds__(256) void f32_to_bf16_kernel(const float* in, u16* out, int n4) {
    int i = blockIdx.x * 256 + threadIdx.x;
    if (i >= n4) return;
    float4 v = ((const float4*)in)[i];
    u16x4 o;
    o[0] = f2bf(v.x); o[1] = f2bf(v.y); o[2] = f2bf(v.z); o[3] = f2bf(v.w);
    ((u16x4*)out)[i] = o;
}

// Merged weight convert+transpose: 4 matrices, f32 [R][C] -> bf16 [C][R] (ldo=2048)
__global__ __launch_bounds__(256) void convT4_kernel(const float* i0, const float* i1,
                                                     const float* i2, const float* i3,
                                                     u16* o0, u16* o1, u16* o2, u16* o3) {
    __shared__ float tile[32][33];
    int z = blockIdx.z;
    const float* in = (z == 0) ? i0 : (z == 1) ? i1 : (z == 2) ? i2 : i3;
    u16* out = (z == 0) ? o0 : (z == 1) ? o1 : (z == 2) ? o2 : o3;
    int ldi = (z == 1 || z == 2) ? 512 : 2048;
    if ((int)blockIdx.x >= (ldi >> 5)) return;
    int cc = threadIdx.x & 31, rb = threadIdx.x >> 5;
    long r0 = (long)blockIdx.y * 32, c0 = (long)blockIdx.x * 32;
#pragma unroll
    for (int i = 0; i < 4; i++)
        tile[rb + i * 8][cc] = in[(r0 + rb + i * 8) * (long)ldi + c0 + cc];
    __syncthreads();
#pragma unroll
    for (int i = 0; i < 4; i++)
        out[(c0 + rb + i * 8) * 2048L + r0 + cc] = f2bf(tile[cc][rb + i * 8]);
}

// Merged RoPE (Q: 16 heads, K: 4 heads at col offset 2048) on bf16 [4096][3072]
__global__ __launch_bounds__(256) void rope2_kernel(u16* QKV, const float* ct, const float* st) {
    int idx = blockIdx.x * 256 + threadIdx.x;      // 655360 total
    int m, hoff, d0;
    if (idx < 524288) {
        m = idx >> 7;
        int rest = idx & 127;
        hoff = (rest >> 3) * 128;
        d0 = (rest & 7) * 8;
    } else {
        int i2 = idx - 524288;
        m = i2 >> 5;
        int rest = i2 & 31;
        hoff = 2048 + (rest >> 3) * 128;
        d0 = (rest & 7) * 8;
    }
    int s = m & 2047;
    u16* p1 = QKV + (long)m * 3072 + hoff + d0;
    u16* p2 = p1 + 64;
    u16x8 v1 = *(const u16x8*)p1;
    u16x8 v2 = *(const u16x8*)p2;
    const float* cp = ct + s * 64 + d0;
    const float* sp = st + s * 64 + d0;
    u16x8 o1, o2;
#pragma unroll
    for (int j = 0; j < 8; j++) {
        float x1 = bf2f(v1[j]), x2 = bf2f(v2[j]);
        float cc = cp[j], ss = sp[j];
        o1[j] = f2bf(x1 * cc - x2 * ss);
        o2[j] = f2bf(x2 * cc + x1 * ss);
    }
    *(u16x8*)p1 = o1;
    *(u16x8*)p2 = o2;
}

// ---------------------------------------------------------------------------
// Deep-pipelined GEMM: C[M][N] = A[M][2048](bf16) * Bt[N][2048](bf16)^T.
// BM=256, BK=32, NBUF=4 LDS ring, prefetch 3 tiles ahead, 1 barrier/K-tile,
// counted vmcnt gate (2*SC except last 2 tiles). 512 thr = 8 waves (WM x WN).
// LDS layout per buffer: A/B tiles as 16B units at [rowgroup][g][row&15]
//   -> every wave-wide ds_read_b128 is 1KB contiguous (conflict-free),
//   -> staging pre-permutes the GLOBAL source (LDS dest stays linear).
// EPI: 0 = f32 out (N=2048), 1 = QKV bf16 (ld 3072) with V written transposed to Vt.
template <int BN, int WN, int EPI>
__global__ __launch_bounds__(512, 2) void gemm_pipe_kernel(const u16* __restrict__ A,
                                                           const u16* __restrict__ Bt,
                                                           void* __restrict__ Cout,
                                                           u16* __restrict__ Vt) {
    constexpr int WM = 8 / WN;
    constexpr int M_REP = (256 / WM) / 16;
    constexpr int N_REP = (BN / WN) / 16;
    constexpr int SC_B = (BN * 64) / 8192;         // stage calls for B (A is 2)
    constexpr int SC = 2 + SC_B;
    constexpr int BUFSZ = 8192 + BN * 32;          // u16 elems per ring slot
    constexpr int NK = 64;                          // K=2048 / 32

    __shared__ u16 lds[4 * BUFSZ];
    const int tid = threadIdx.x;
    const int w = tid >> 6, l = tid & 63, g = l >> 4, c = l & 15;
    const int wr = w / WN, wc = w % WN;
    const long m0 = (long)blockIdx.y * 256, n0 = (long)blockIdx.x * BN;

    // Pre-permuted global source pointers (u16 elems), one per stage call.
    const u16* srcA[2];
    const u16* srcB[SC_B];
#pragma unroll
    for (int j = 0; j < 2; j++) {
        int x = j * 8192 + tid * 16;               // byte offset within A region
        int row = ((x >> 10) << 4) | ((x >> 4) & 15);
        int g8 = ((x >> 8) & 3) * 8;
        srcA[j] = A + (size_t)(m0 + row) * 2048 + g8;
    }
#pragma unroll
    for (int j = 0; j < SC_B; j++) {
        int x = j * 8192 + tid * 16;
        int row = ((x >> 10) << 4) | ((x >> 4) & 15);
        int g8 = ((x >> 8) & 3) * 8;
        srcB[j] = Bt + (size_t)(n0 + row) * 2048 + g8;
    }

    auto stage = [&](int t) {
        const int bb = t & 3;
#pragma unroll
        for (int j = 0; j < 2; j++)
            gload_lds16(srcA[j] + t * 32, (void*)&lds[bb * BUFSZ + j * 4096 + tid * 8]);
#pragma unroll
        for (int j = 0; j < SC_B; j++)
            gload_lds16(srcB[j] + t * 32, (void*)&lds[bb * BUFSZ + 8192 + j * 4096 + tid * 8]);
    };

    f32x4 acc[M_REP][N_REP];
    const f32x4 zero = {0.f, 0.f, 0.f, 0.f};
#pragma unroll
    for (int i = 0; i < M_REP; i++)
#pragma unroll
        for (int j = 0; j < N_REP; j++) acc[i][j] = zero;

    stage(0);
    stage(1);
    stage(2);

    for (int kt = 0; kt < NK; ++kt) {
        const int buf = kt & 3;
        // gate: tile kt's stages (issued at kt-3) must have landed;
        // tiles kt+1, kt+2 (2*SC loads) may stay in flight.
        if (kt <= NK - 3) {
            if constexpr (SC == 4) WAITV(8); else WAITV(6);
        } else if (kt == NK - 2) {
            if constexpr (SC == 4) WAITV(4); else WAITV(3);
        } else {
            WAITV(0);
        }
        __builtin_amdgcn_s_barrier();
        __builtin_amdgcn_sched_barrier(0);
        asm volatile("" ::: "memory");

        if (kt + 3 < NK) stage(kt + 3);            // into buf (kt-1)&3, freed by barrier

        const u16* bp = &lds[buf * BUFSZ];
        bf16x8 af[M_REP], bfr[N_REP];
#pragma unroll
        for (int nj = 0; nj < N_REP; nj++)
            bfr[nj] = *(const bf16x8*)&bp[8192 + (wc * N_REP + nj) * 512 + l * 8];
#pragma unroll
        for (int mi = 0; mi < M_REP; mi++)
            af[mi] = *(const bf16x8*)&bp[(wr * M_REP + mi) * 512 + l * 8];

        __builtin_amdgcn_s_setprio(1);
#pragma unroll
        for (int mi = 0; mi < M_REP; mi++)
#pragma unroll
            for (int nj = 0; nj < N_REP; nj++)
                acc[mi][nj] = mfma32(af[mi], bfr[nj], acc[mi][nj]);
        __builtin_amdgcn_s_setprio(0);
    }

    // ---- epilogue ----
    if (EPI == 0) {
        float* C = (float*)Cout;
#pragma unroll
        for (int mi = 0; mi < M_REP; mi++)
#pragma unroll
            for (int nj = 0; nj < N_REP; nj++) {
                long row0 = m0 + wr * (256 / WM) + mi * 16 + g * 4;
                long col = n0 + wc * (BN / WN) + nj * 16 + c;
#pragma unroll
                for (int r = 0; r < 4; r++)
                    C[(row0 + r) * 2048 + col] = acc[mi][nj][r];
            }
    } else {
        u16* Cq = (u16*)Cout;
        if (n0 < 2560) {                            // Q/K region -> QKV (ld 3072)
#pragma unroll
            for (int mi = 0; mi < M_REP; mi++)
#pragma unroll
                for (int nj = 0; nj < N_REP; nj++) {
                    long row0 = m0 + wr * (256 / WM) + mi * 16 + g * 4;
                    long col = n0 + wc * (BN / WN) + nj * 16 + c;
#pragma unroll
                    for (int r = 0; r < 4; r++)
                        Cq[(row0 + r) * 3072 + col] = f2bf(acc[mi][nj][r]);
                }
        } else {                                    // V region -> Vt transposed
#pragma unroll
            for (int mi = 0; mi < M_REP; mi++)
#pragma unroll
                for (int nj = 0; nj < N_REP; nj++) {
                    long row0 = m0 + wr * (256 / WM) + mi * 16 + g * 4;
                    long b = row0 >> 11, s0 = row0 & 2047;
                    long dglob = n0 + wc * (BN / WN) + nj * 16 + c - 2560;
                    u16x4 pk;
                    pk[0] = f2bf(acc[mi][nj][0]); pk[1] = f2bf(acc[mi][nj][1]);
                    pk[2] = f2bf(acc[mi][nj][2]); pk[3] = f2bf(acc[mi][nj][3]);
                    *(u16x4*)&Vt[(b * 512 + dglob) * 2048 + s0] = pk;
                }
        }
    }
}

// ---------------------------------------------------------------------------
// Flash sliding-window GQA (unchanged from R1).
#define ATT_SCALE 0.08838834764831845f
#define L2E 1.4426950408889634f

__global__ __launch_bounds__(256) void attn_kernel(const u16* QKV, const u16* Vt, u16* AO) {
    __shared__ u16 Ks[64 * 128];
    __shared__ u16 Vs[128 * 64];
    const int tid = threadIdx.x;
    const int w = tid >> 6, l = tid & 63, g = l >> 4, c = l & 15;
    const int Tq = blockIdx.x;
    const int h = blockIdx.y;
    const int b = blockIdx.z;
    const int kvh = h >> 2;
    const int q0 = Tq * 64;
    const int qb = q0 + w * 16;

    bf16x8 bq[4];
    {
        const u16* qrow = QKV + (long)(b * 2048 + qb + c) * 3072 + h * 128;
#pragma unroll
        for (int kc = 0; kc < 4; kc++) bq[kc] = *(const bf16x8*)(qrow + kc * 32 + g * 8);
    }

    f32x4 acc_o[8];
    const f32x4 zero = {0.f, 0.f, 0.f, 0.f};
#pragma unroll
    for (int i = 0; i < 8; i++) acc_o[i] = zero;
    float m_run = -3.0e38f, l_run = 0.f;

    const int t_lo = (q0 > 511) ? ((q0 - 511) >> 6) : 0;
    const int t_hi = Tq;

    for (int t = t_lo; t <= t_hi; ++t) {
        const int kv0 = t * 64;
#pragma unroll
        for (int i = 0; i < 4; i++) {
            int o = (i * 256 + tid) * 16;
            int key = o >> 8;
            int cl = ((o >> 4) & 15) ^ (key & 15);
            gload_lds16(QKV + (long)(b * 2048 + kv0 + key) * 3072 + 2048 + kvh * 128 + cl * 8,
                        (void*)&Ks[(i * 256 + w * 64) * 8]);
        }
#pragma unroll
        for (int i = 0; i < 4; i++) {
            int o = (i * 256 + tid) * 16;
            int d = o >> 7;
            int cl = ((o >> 4) & 7) ^ (d & 7);
            gload_lds16(Vt + (long)((b * 4 + kvh) * 128 + d) * 2048 + kv0 + cl * 8,
                        (void*)&Vs[(i * 256 + w * 64) * 8]);
        }
        __syncthreads();

        f32x4 sacc[4];
#pragma unroll
        for (int n = 0; n < 4; n++) {
            sacc[n] = zero;
#pragma unroll
            for (int kc = 0; kc < 4; kc++) {
                int row = n * 16 + c;
                int ch = (kc * 4 + g) ^ c;
                bf16x8 kf = *(const bf16x8*)&Ks[row * 128 + ch * 8];
                sacc[n] = mfma32(kf, bq[kc], sacc[n]);
            }
        }

        const bool edge = (kv0 + 63 > qb) || (kv0 < qb + 15 - 511);
        float p[4][4];
        float m_tile = -3.0e38f;
#pragma unroll
        for (int n = 0; n < 4; n++)
#pragma unroll
            for (int r = 0; r < 4; r++) {
                float s = sacc[n][r] * ATT_SCALE;
                if (edge) {
                    int j = kv0 + n * 16 + 4 * g + r;
                    int q = qb + c;
                    if (j > q || j < q - 511) s = -__builtin_inff();
                }
                p[n][r] = s;
                m_tile = fmaxf(m_tile, s);
            }
        m_tile = fmaxf(m_tile, __shfl_xor(m_tile, 16));
        m_tile = fmaxf(m_tile, __shfl_xor(m_tile, 32));
        float m_new = fmaxf(m_run, m_tile);
        float alpha = exp2f((m_run - m_new) * L2E);
        float lsum = 0.f;
#pragma unroll
        for (int n = 0; n < 4; n++)
#pragma unroll
            for (int r = 0; r < 4; r++) {
                float e = exp2f((p[n][r] - m_new) * L2E);
                p[n][r] = e;
                lsum += e;
            }
        lsum += __shfl_xor(lsum, 16);
        lsum += __shfl_xor(lsum, 32);
        l_run = l_run * alpha + lsum;
        m_run = m_new;

        float alpha_r[4];
#pragma unroll
        for (int r = 0; r < 4; r++) alpha_r[r] = __shfl(alpha, (g << 4) + 4 * g + r);
#pragma unroll
        for (int dn = 0; dn < 8; dn++) {
            f32x4 t2 = acc_o[dn];
            t2[0] *= alpha_r[0]; t2[1] *= alpha_r[1];
            t2[2] *= alpha_r[2]; t2[3] *= alpha_r[3];
            acc_o[dn] = t2;
        }

        bf16x4 ap[4];
#pragma unroll
        for (int n = 0; n < 4; n++) {
            union { u16x4 u; bf16x4 b; } pk;
            pk.u[0] = f2bf(p[n][0]); pk.u[1] = f2bf(p[n][1]);
            pk.u[2] = f2bf(p[n][2]); pk.u[3] = f2bf(p[n][3]);
            ap[n] = pk.b;
        }

#pragma unroll
        for (int n = 0; n < 4; n++)
#pragma unroll
            for (int dn = 0; dn < 8; dn++) {
                int row = dn * 16 + c;
                int ch = (2 * n + (g >> 1)) ^ (c & 7);
                bf16x4 vf = *(const bf16x4*)&Vs[row * 64 + ch * 8 + (g & 1) * 4];
                acc_o[dn] = mfma16(ap[n], vf, acc_o[dn]);
            }
        __syncthreads();
    }

    float lr[4];
#pragma unroll
    for (int r = 0; r < 4; r++) {
        float lq = __shfl(l_run, (g << 4) + 4 * g + r);
        lr[r] = 1.f / lq;
    }
#pragma unroll
    for (int dn = 0; dn < 8; dn++)
#pragma unroll
        for (int r = 0; r < 4; r++) {
            long row = (long)(b * 2048 + qb + 4 * g + r);
            AO[row * 2048 + h * 128 + dn * 16 + c] = f2bf(acc_o[dn][r] * lr[r]);
        }
}

// ---------------------------------------------------------------------------
extern "C" void kernel_launch(void* const* d_in, const int* in_sizes, int n_in,
                              void* d_out, int out_size, void* d_ws, size_t ws_size,
                              hipStream_t stream) {
    const float* x = (const float*)d_in[0];
    const float* wq = (const float*)d_in[1];
    const float* wk = (const float*)d_in[2];
    const float* wv = (const float*)d_in[3];
    const float* wo = (const float*)d_in[4];
    float* out = (float*)d_out;

    char* ws = (char*)d_ws;
    u16* xb = (u16*)(ws);                         // [4096][2048]        16.78 MB
    u16* wAll = (u16*)(ws + 16777216);            // [3072][2048] (BT)   12.58 MB
    u16* woT = (u16*)(ws + 29360128);             // [2048][2048] (BT)    8.39 MB
    u16* QKV = (u16*)(ws + 37748736);             // [4096][3072]        25.17 MB
    u16* Vt = (u16*)(ws + 62914560);              // [1024][2048]         4.19 MB
    u16* AO = (u16*)(ws + 67108864);              // [4096][2048]        16.78 MB
    float* ct = (float*)(ws + 83886080);          // [2048][64]
    float* st = (float*)(ws + 84410368);          // [2048][64]

    sincos_kernel<<<512, 256, 0, stream>>>(ct, st);
    f32_to_bf16_kernel<<<8192, 256, 0, stream>>>(x, xb, 2097152);
    convT4_kernel<<<dim3(64, 64, 4), 256, 0, stream>>>(
        wq, wk, wv, wo, wAll, wAll + (long)2048 * 2048, wAll + (long)2560 * 2048, woT);

    // QKV = xb @ wAll^T (V columns written transposed into Vt)
    gemm_pipe_kernel<256, 4, 1><<<dim3(12, 16), 512, 0, stream>>>(xb, wAll, QKV, Vt);

    rope2_kernel<<<2560, 256, 0, stream>>>(QKV, ct, st);

    attn_kernel<<<dim3(32, 16, 2), 256, 0, stream>>>(QKV, Vt, AO);

    // out = AO @ woT^T
    gemm_pipe_kernel<128, 2, 0><<<dim3(16, 16), 512, 0, stream>>>(AO, woT, out, nullptr);
}

// Round 3
// 208.112 us; speedup vs baseline: 1.0036x; 1.0036x over previous
//
#include <hip/hip_runtime.h>
#include <math.h>

// ---------------------------------------------------------------------------
// SlidingWindowGQA: x[2,2048,2048] f32, wq[2048,2048], wk/wv[2048,512], wo[2048,2048]
// out f32 [2,2048,2048].  B=2 S=2048 H=16 KVH=4 D=128 WINDOW=512.
// R3: 8-phase 256-wide GEMM (2 barriers/phase, one vmcnt(2) gate per K-tile,
//     linear LDS + permuted global source = conflict-free), exact-fill out-GEMM.
// ---------------------------------------------------------------------------

typedef unsigned short u16;
typedef __attribute__((ext_vector_type(4))) float f32x4;
typedef __attribute__((ext_vector_type(8))) __bf16 bf16x8;
typedef __attribute__((ext_vector_type(4))) __bf16 bf16x4;
typedef __attribute__((ext_vector_type(4))) short s16x4;
typedef __attribute__((ext_vector_type(8))) unsigned short u16x8;
typedef __attribute__((ext_vector_type(4))) unsigned short u16x4;

#define DEV static __device__ __forceinline__
#define WAITV(n) asm volatile("s_waitcnt vmcnt(" #n ")" ::: "memory")
#define BAR __builtin_amdgcn_s_barrier()
#define LGKM0 do { asm volatile("s_waitcnt lgkmcnt(0)" ::: "memory"); \
                   __builtin_amdgcn_sched_barrier(0); } while (0)
#define LGKM8 asm volatile("s_waitcnt lgkmcnt(8)" ::: "memory")

DEV float bf2f(u16 h) {
    union { unsigned int i; float f; } x;
    x.i = ((unsigned int)h) << 16;
    return x.f;
}
DEV u16 f2bf(float f) {
    union { float f; unsigned int i; } x;
    x.f = f;
    unsigned int u = x.i;
    return (u16)((u + 0x7FFFu + ((u >> 16) & 1u)) >> 16);
}

DEV f32x4 mfma32(bf16x8 a, bf16x8 b, f32x4 c) {
    return __builtin_amdgcn_mfma_f32_16x16x32_bf16(a, b, c, 0, 0, 0);
}
DEV f32x4 mfma16(bf16x4 a, bf16x4 b, f32x4 c) {
#if __has_builtin(__builtin_amdgcn_mfma_f32_16x16x16_bf16)
    return __builtin_amdgcn_mfma_f32_16x16x16_bf16(a, b, c, 0, 0, 0);
#else
    union { bf16x4 v; s16x4 s; } ua, ub;
    ua.v = a; ub.v = b;
    return __builtin_amdgcn_mfma_f32_16x16x16bf16_1k(ua.s, ub.s, c, 0, 0, 0);
#endif
}

DEV void gload_lds16(const void* g, void* lds) {
    __builtin_amdgcn_global_load_lds(
        (const __attribute__((address_space(1))) unsigned int*)g,
        (__attribute__((address_space(3))) unsigned int*)lds, 16, 0, 0);
}

// ---------------------------------------------------------------------------
__global__ __launch_bounds__(256) void sincos_kernel(float* ct, float* st) {
    int idx = blockIdx.x * 256 + threadIdx.x;      // 131072 total
    int s = idx >> 6, d = idx & 63;
    float inv = exp2f(-(float)d * (13.287712379549449f / 64.f));
    float a = (float)s * inv;
    float sv, cv;
    sincosf(a, &sv, &cv);
    ct[idx] = cv;
    st[idx] = sv;
}

__global__ __launch_bounds__(256) void f32_to_bf16_kernel(const float* in, u16* out, int n4) {
    int i = blockIdx.x * 256 + threadIdx.x;
    if (i >= n4) return;
    float4 v = ((const float4*)in)[i];
    u16x4 o;
    o[0] = f2bf(v.x); o[1] = f2bf(v.y); o[2] = f2bf(v.z); o[3] = f2bf(v.w);
    ((u16x4*)out)[i] = o;
}

// Merged weight convert+transpose: 4 matrices, f32 [R][C] -> bf16 [C][R] (ldo=2048)
__global__ __launch_bounds__(256) void convT4_kernel(const float* i0, const float* i1,
                                                     const float* i2, const float* i3,
                                                     u16* o0, u16* o1, u16* o2, u16* o3) {
    __shared__ float tile[32][33];
    int z = blockIdx.z;
    const float* in = (z == 0) ? i0 : (z == 1) ? i1 : (z == 2) ? i2 : i3;
    u16* out = (z == 0) ? o0 : (z == 1) ? o1 : (z == 2) ? o2 : o3;
    int ldi = (z == 1 || z == 2) ? 512 : 2048;
    if ((int)blockIdx.x >= (ldi >> 5)) return;
    int cc = threadIdx.x & 31, rb = threadIdx.x >> 5;
    long r0 = (long)blockIdx.y * 32, c0 = (long)blockIdx.x * 32;
#pragma unroll
    for (int i = 0; i < 4; i++)
        tile[rb + i * 8][cc] = in[(r0 + rb + i * 8) * (long)ldi + c0 + cc];
    __syncthreads();
#pragma unroll
    for (int i = 0; i < 4; i++)
        out[(c0 + rb + i * 8) * 2048L + r0 + cc] = f2bf(tile[cc][rb + i * 8]);
}

// Merged RoPE (Q: 16 heads, K: 4 heads at col offset 2048) on bf16 [4096][3072]
__global__ __launch_bounds__(256) void rope2_kernel(u16* QKV, const float* ct, const float* st) {
    int idx = blockIdx.x * 256 + threadIdx.x;      // 655360 total
    int m, hoff, d0;
    if (idx < 524288) {
        m = idx >> 7;
        int rest = idx & 127;
        hoff = (rest >> 3) * 128;
        d0 = (rest & 7) * 8;
    } else {
        int i2 = idx - 524288;
        m = i2 >> 5;
        int rest = i2 & 31;
        hoff = 2048 + (rest >> 3) * 128;
        d0 = (rest & 7) * 8;
    }
    int s = m & 2047;
    u16* p1 = QKV + (long)m * 3072 + hoff + d0;
    u16* p2 = p1 + 64;
    u16x8 v1 = *(const u16x8*)p1;
    u16x8 v2 = *(const u16x8*)p2;
    const float* cp = ct + s * 64 + d0;
    const float* sp = st + s * 64 + d0;
    u16x8 o1, o2;
#pragma unroll
    for (int j = 0; j < 8; j++) {
        float x1 = bf2f(v1[j]), x2 = bf2f(v2[j]);
        float cc = cp[j], ss = sp[j];
        o1[j] = f2bf(x1 * cc - x2 * ss);
        o2[j] = f2bf(x2 * cc + x1 * ss);
    }
    *(u16x8*)p1 = o1;
    *(u16x8*)p2 = o2;
}

// ---------------------------------------------------------------------------
// 8-phase GEMM: C[M][N] = A[M][2048](bf16,row) * Bt[N][2048](bf16,row)^T.
// BM=256, BK=64 (2 kk-sub-steps of 32), 8 waves (WMxWN), 2-buffer LDS.
// Per K-tile: 4 phases {ds_read quadrant frags; stage 1 half-tile; bar;
//   lgkmcnt(0); setprio(1); MH*NH*2 MFMA; setprio(0); [gate]; bar}.
// Stage stagger: group t stages Ah1,Bh0,Bh1 of t+1 at p0..p2, Ah0 of t+2 at p3.
// Lifetimes: A-region of buf last read at p2, B-region at p3 -> writes safe.
// Gate: one vmcnt(2) per K-tile (allow t+2's Ah0 in flight); NK-2: vmcnt(0).
// LDS (16B units, linear): A: [half][kk][rowgroup&7][row16]; B analogous.
// Global source pre-permuted so each wave ds_read_b128 = 1KB contiguous.
template <int BN, int WN, int EPI>
__global__ __launch_bounds__(512, 2) void gemm8_kernel(const u16* __restrict__ A,
                                                       const u16* __restrict__ Bt,
                                                       void* __restrict__ Cout,
                                                       u16* __restrict__ Vt) {
    constexpr int WM = 8 / WN;
    constexpr int MR = 16 / WM;          // A frags per wave
    constexpr int NR = BN / WN / 16;     // B frags per wave
    constexpr int MH = MR / 2, NH = NR / 2;
    constexpr int BSZ = BN * 64;         // B u16 per buffer
    constexpr int BUFSZ = 16384 + BSZ;
    constexpr int NK = 32;               // 2048 / 64

    __shared__ u16 lds[2 * BUFSZ];
    const int tid = threadIdx.x;
    const int w = tid >> 6, l = tid & 63, g = l >> 4, c = l & 15;
    const int wr = w / WN, wc = w % WN;
    const long m0 = (long)blockIdx.y * 256, n0 = (long)blockIdx.x * BN;

    const int rowS = ((tid >> 6) << 4) | (tid & 15);
    const int ggS = ((tid >> 4) & 3) * 8;

    auto stageA = [&](int t, int h, int j) {
        gload_lds16(A + (size_t)(m0 + h * 128 + rowS) * 2048 + t * 64 + j * 32 + ggS,
                    (void*)&lds[(t & 1) * BUFSZ + h * 8192 + j * 4096 + (tid << 3)]);
    };
    auto stageB = [&](int t, int h, int j) {
        if constexpr (BN == 256) {
            gload_lds16(Bt + (size_t)(n0 + h * 128 + rowS) * 2048 + t * 64 + j * 32 + ggS,
                        (void*)&lds[(t & 1) * BUFSZ + 16384 + h * 8192 + j * 4096 + (tid << 3)]);
        } else {
            gload_lds16(Bt + (size_t)(n0 + h * 64 + (((tid >> 6) & 3) << 4) + (tid & 15)) * 2048
                            + t * 64 + (tid >> 8) * 32 + ggS,
                        (void*)&lds[(t & 1) * BUFSZ + 16384 + h * 4096 + (tid << 3)]);
        }
    };
    auto stageAh = [&](int t, int h) { stageA(t, h, 0); stageA(t, h, 1); };
    auto stageBh = [&](int t, int h) {
        if constexpr (BN == 256) { stageB(t, h, 0); stageB(t, h, 1); }
        else stageB(t, h, 0);
    };

    auto readA = [&](int b, int mi, int kk) -> bf16x8 {
        int rg = wr * MR + mi;
        return *(const bf16x8*)&lds[b * BUFSZ + (rg >> 3) * 8192 + kk * 4096 +
                                    (rg & 7) * 512 + l * 8];
    };
    auto readB = [&](int b, int nj, int kk) -> bf16x8 {
        int rg = wc * NR + nj;
        if constexpr (BN == 256)
            return *(const bf16x8*)&lds[b * BUFSZ + 16384 + (rg >> 3) * 8192 + kk * 4096 +
                                        (rg & 7) * 512 + l * 8];
        else
            return *(const bf16x8*)&lds[b * BUFSZ + 16384 + (rg >> 2) * 4096 + kk * 2048 +
                                        (rg & 3) * 512 + l * 8];
    };

    f32x4 acc[MR][NR];
    const f32x4 zero = {0.f, 0.f, 0.f, 0.f};
#pragma unroll
    for (int i = 0; i < MR; i++)
#pragma unroll
        for (int j = 0; j < NR; j++) acc[i][j] = zero;

    // prologue: all of t0, plus Ah0 of t1 (last 2 loads allowed outstanding)
    stageAh(0, 0); stageAh(0, 1);
    stageBh(0, 0); stageBh(0, 1);
    stageAh(1, 0);
    WAITV(2);
    BAR;

    bf16x8 fa[MH][2], fb[NH][2];

    for (int t = 0; t < NK; ++t) {
        const int b = t & 1;
        // ---- p0: A-low + B-low reads; stage Ah1(t+1)
#pragma unroll
        for (int mi = 0; mi < MH; mi++)
#pragma unroll
            for (int kk = 0; kk < 2; kk++) fa[mi][kk] = readA(b, mi, kk);
#pragma unroll
        for (int nj = 0; nj < NH; nj++)
#pragma unroll
            for (int kk = 0; kk < 2; kk++) fb[nj][kk] = readB(b, nj, kk);
        if (t + 1 < NK) stageAh(t + 1, 1);
        if constexpr (2 * (MH + NH) >= 12) LGKM8;
        BAR; LGKM0;
        __builtin_amdgcn_s_setprio(1);
#pragma unroll
        for (int mi = 0; mi < MH; mi++)
#pragma unroll
            for (int nj = 0; nj < NH; nj++)
#pragma unroll
                for (int kk = 0; kk < 2; kk++)
                    acc[mi][nj] = mfma32(fa[mi][kk], fb[nj][kk], acc[mi][nj]);
        __builtin_amdgcn_s_setprio(0);
        BAR;
        // ---- p1: B-high reads; stage Bh0(t+1)
#pragma unroll
        for (int nj = 0; nj < NH; nj++)
#pragma unroll
            for (int kk = 0; kk < 2; kk++) fb[nj][kk] = readB(b, NH + nj, kk);
        if (t + 1 < NK) stageBh(t + 1, 0);
        BAR; LGKM0;
        __builtin_amdgcn_s_setprio(1);
#pragma unroll
        for (int mi = 0; mi < MH; mi++)
#pragma unroll
            for (int nj = 0; nj < NH; nj++)
#pragma unroll
                for (int kk = 0; kk < 2; kk++)
                    acc[mi][NH + nj] = mfma32(fa[mi][kk], fb[nj][kk], acc[mi][NH + nj]);
        __builtin_amdgcn_s_setprio(0);
        BAR;
        // ---- p2: A-high reads; stage Bh1(t+1)
#pragma unroll
        for (int mi = 0; mi < MH; mi++)
#pragma unroll
            for (int kk = 0; kk < 2; kk++) fa[mi][kk] = readA(b, MH + mi, kk);
        if (t + 1 < NK) stageBh(t + 1, 1);
        BAR; LGKM0;
        __builtin_amdgcn_s_setprio(1);
#pragma unroll
        for (int mi = 0; mi < MH; mi++)
#pragma unroll
            for (int nj = 0; nj < NH; nj++)
#pragma unroll
                for (int kk = 0; kk < 2; kk++)
                    acc[MH + mi][NH + nj] = mfma32(fa[mi][kk], fb[nj][kk], acc[MH + mi][NH + nj]);
        __builtin_amdgcn_s_setprio(0);
        BAR;
        // ---- p3: B-low re-reads; stage Ah0(t+2)
#pragma unroll
        for (int nj = 0; nj < NH; nj++)
#pragma unroll
            for (int kk = 0; kk < 2; kk++) fb[nj][kk] = readB(b, nj, kk);
        if (t + 2 < NK) stageAh(t + 2, 0);
        BAR; LGKM0;
        __builtin_amdgcn_s_setprio(1);
#pragma unroll
        for (int mi = 0; mi < MH; mi++)
#pragma unroll
            for (int nj = 0; nj < NH; nj++)
#pragma unroll
                for (int kk = 0; kk < 2; kk++)
                    acc[MH + mi][nj] = mfma32(fa[mi][kk], fb[nj][kk], acc[MH + mi][nj]);
        __builtin_amdgcn_s_setprio(0);
        if (t <= NK - 3) { WAITV(2); }
        else if (t == NK - 2) { WAITV(0); }
        BAR;
    }

    // ---- epilogue ----
    if (EPI == 0) {
        float* C = (float*)Cout;
#pragma unroll
        for (int mi = 0; mi < MR; mi++)
#pragma unroll
            for (int nj = 0; nj < NR; nj++) {
                long row0 = m0 + wr * (256 / WM) + mi * 16 + g * 4;
                long col = n0 + wc * (BN / WN) + nj * 16 + c;
#pragma unroll
                for (int r = 0; r < 4; r++)
                    C[(row0 + r) * 2048 + col] = acc[mi][nj][r];
            }
    } else {
        u16* Cq = (u16*)Cout;
        if (n0 < 2560) {                            // Q/K region -> QKV (ld 3072)
#pragma unroll
            for (int mi = 0; mi < MR; mi++)
#pragma unroll
                for (int nj = 0; nj < NR; nj++) {
                    long row0 = m0 + wr * (256 / WM) + mi * 16 + g * 4;
                    long col = n0 + wc * (BN / WN) + nj * 16 + c;
#pragma unroll
                    for (int r = 0; r < 4; r++)
                        Cq[(row0 + r) * 3072 + col] = f2bf(acc[mi][nj][r]);
                }
        } else {                                    // V region -> Vt transposed
#pragma unroll
            for (int mi = 0; mi < MR; mi++)
#pragma unroll
                for (int nj = 0; nj < NR; nj++) {
                    long row0 = m0 + wr * (256 / WM) + mi * 16 + g * 4;
                    long b = row0 >> 11, s0 = row0 & 2047;
                    long dglob = n0 + wc * (BN / WN) + nj * 16 + c - 2560;
                    u16x4 pk;
                    pk[0] = f2bf(acc[mi][nj][0]); pk[1] = f2bf(acc[mi][nj][1]);
                    pk[2] = f2bf(acc[mi][nj][2]); pk[3] = f2bf(acc[mi][nj][3]);
                    *(u16x4*)&Vt[(b * 512 + dglob) * 2048 + s0] = pk;
                }
        }
    }
}

// ---------------------------------------------------------------------------
// Flash sliding-window GQA (unchanged).
#define ATT_SCALE 0.08838834764831845f
#define L2E 1.4426950408889634f

__global__ __launch_bounds__(256) void attn_kernel(const u16* QKV, const u16* Vt, u16* AO) {
    __shared__ u16 Ks[64 * 128];
    __shared__ u16 Vs[128 * 64];
    const int tid = threadIdx.x;
    const int w = tid >> 6, l = tid & 63, g = l >> 4, c = l & 15;
    const int Tq = blockIdx.x;
    const int h = blockIdx.y;
    const int b = blockIdx.z;
    const int kvh = h >> 2;
    const int q0 = Tq * 64;
    const int qb = q0 + w * 16;

    bf16x8 bq[4];
    {
        const u16* qrow = QKV + (long)(b * 2048 + qb + c) * 3072 + h * 128;
#pragma unroll
        for (int kc = 0; kc < 4; kc++) bq[kc] = *(const bf16x8*)(qrow + kc * 32 + g * 8);
    }

    f32x4 acc_o[8];
    const f32x4 zero = {0.f, 0.f, 0.f, 0.f};
#pragma unroll
    for (int i = 0; i < 8; i++) acc_o[i] = zero;
    float m_run = -3.0e38f, l_run = 0.f;

    const int t_lo = (q0 > 511) ? ((q0 - 511) >> 6) : 0;
    const int t_hi = Tq;

    for (int t = t_lo; t <= t_hi; ++t) {
        const int kv0 = t * 64;
#pragma unroll
        for (int i = 0; i < 4; i++) {
            int o = (i * 256 + tid) * 16;
            int key = o >> 8;
            int cl = ((o >> 4) & 15) ^ (key & 15);
            gload_lds16(QKV + (long)(b * 2048 + kv0 + key) * 3072 + 2048 + kvh * 128 + cl * 8,
                        (void*)&Ks[(i * 256 + w * 64) * 8]);
        }
#pragma unroll
        for (int i = 0; i < 4; i++) {
            int o = (i * 256 + tid) * 16;
            int d = o >> 7;
            int cl = ((o >> 4) & 7) ^ (d & 7);
            gload_lds16(Vt + (long)((b * 4 + kvh) * 128 + d) * 2048 + kv0 + cl * 8,
                        (void*)&Vs[(i * 256 + w * 64) * 8]);
        }
        __syncthreads();

        f32x4 sacc[4];
#pragma unroll
        for (int n = 0; n < 4; n++) {
            sacc[n] = zero;
#pragma unroll
            for (int kc = 0; kc < 4; kc++) {
                int row = n * 16 + c;
                int ch = (kc * 4 + g) ^ c;
                bf16x8 kf = *(const bf16x8*)&Ks[row * 128 + ch * 8];
                sacc[n] = mfma32(kf, bq[kc], sacc[n]);
            }
        }

        const bool edge = (kv0 + 63 > qb) || (kv0 < qb + 15 - 511);
        float p[4][4];
        float m_tile = -3.0e38f;
#pragma unroll
        for (int n = 0; n < 4; n++)
#pragma unroll
            for (int r = 0; r < 4; r++) {
                float s = sacc[n][r] * ATT_SCALE;
                if (edge) {
                    int j = kv0 + n * 16 + 4 * g + r;
                    int q = qb + c;
                    if (j > q || j < q - 511) s = -__builtin_inff();
                }
                p[n][r] = s;
                m_tile = fmaxf(m_tile, s);
            }
        m_tile = fmaxf(m_tile, __shfl_xor(m_tile, 16));
        m_tile = fmaxf(m_tile, __shfl_xor(m_tile, 32));
        float m_new = fmaxf(m_run, m_tile);
        float alpha = exp2f((m_run - m_new) * L2E);
        float lsum = 0.f;
#pragma unroll
        for (int n = 0; n < 4; n++)
#pragma unroll
            for (int r = 0; r < 4; r++) {
                float e = exp2f((p[n][r] - m_new) * L2E);
                p[n][r] = e;
                lsum += e;
            }
        lsum += __shfl_xor(lsum, 16);
        lsum += __shfl_xor(lsum, 32);
        l_run = l_run * alpha + lsum;
        m_run = m_new;

        float alpha_r[4];
#pragma unroll
        for (int r = 0; r < 4; r++) alpha_r[r] = __shfl(alpha, (g << 4) + 4 * g + r);
#pragma unroll
        for (int dn = 0; dn < 8; dn++) {
            f32x4 t2 = acc_o[dn];
            t2[0] *= alpha_r[0]; t2[1] *= alpha_r[1];
            t2[2] *= alpha_r[2]; t2[3] *= alpha_r[3];
            acc_o[dn] = t2;
        }

        bf16x4 ap[4];
#pragma unroll
        for (int n = 0; n < 4; n++) {
            union { u16x4 u; bf16x4 b; } pk;
            pk.u[0] = f2bf(p[n][0]); pk.u[1] = f2bf(p[n][1]);
            pk.u[2] = f2bf(p[n][2]); pk.u[3] = f2bf(p[n][3]);
            ap[n] = pk.b;
        }

#pragma unroll
        for (int n = 0; n < 4; n++)
#pragma unroll
            for (int dn = 0; dn < 8; dn++) {
                int row = dn * 16 + c;
                int ch = (2 * n + (g >> 1)) ^ (c & 7);
                bf16x4 vf = *(const bf16x4*)&Vs[row * 64 + ch * 8 + (g & 1) * 4];
                acc_o[dn] = mfma16(ap[n], vf, acc_o[dn]);
            }
        __syncthreads();
    }

    float lr[4];
#pragma unroll
    for (int r = 0; r < 4; r++) {
        float lq = __shfl(l_run, (g << 4) + 4 * g + r);
        lr[r] = 1.f / lq;
    }
#pragma unroll
    for (int dn = 0; dn < 8; dn++)
#pragma unroll
        for (int r = 0; r < 4; r++) {
            long row = (long)(b * 2048 + qb + 4 * g + r);
            AO[row * 2048 + h * 128 + dn * 16 + c] = f2bf(acc_o[dn][r] * lr[r]);
        }
}

// ---------------------------------------------------------------------------
extern "C" void kernel_launch(void* const* d_in, const int* in_sizes, int n_in,
                              void* d_out, int out_size, void* d_ws, size_t ws_size,
                              hipStream_t stream) {
    const float* x = (const float*)d_in[0];
    const float* wq = (const float*)d_in[1];
    const float* wk = (const float*)d_in[2];
    const float* wv = (const float*)d_in[3];
    const float* wo = (const float*)d_in[4];
    float* out = (float*)d_out;

    char* ws = (char*)d_ws;
    u16* xb = (u16*)(ws);                         // [4096][2048]        16.78 MB
    u16* wAll = (u16*)(ws + 16777216);            // [3072][2048] (BT)   12.58 MB
    u16* woT = (u16*)(ws + 29360128);             // [2048][2048] (BT)    8.39 MB
    u16* QKV = (u16*)(ws + 37748736);             // [4096][3072]        25.17 MB
    u16* Vt = (u16*)(ws + 62914560);              // [1024][2048]         4.19 MB
    u16* AO = (u16*)(ws + 67108864);              // [4096][2048]        16.78 MB
    float* ct = (float*)(ws + 83886080);          // [2048][64]
    float* st = (float*)(ws + 84410368);          // [2048][64]

    sincos_kernel<<<512, 256, 0, stream>>>(ct, st);
    f32_to_bf16_kernel<<<8192, 256, 0, stream>>>(x, xb, 2097152);
    convT4_kernel<<<dim3(64, 64, 4), 256, 0, stream>>>(
        wq, wk, wv, wo, wAll, wAll + (long)2048 * 2048, wAll + (long)2560 * 2048, woT);

    // QKV = xb @ wAll^T (V columns written transposed into Vt)
    gemm8_kernel<256, 4, 1><<<dim3(12, 16), 512, 0, stream>>>(xb, wAll, QKV, Vt);

    rope2_kernel<<<2560, 256, 0, stream>>>(QKV, ct, st);

    attn_kernel<<<dim3(32, 16, 2), 256, 0, stream>>>(QKV, Vt, AO);

    // out = AO @ woT^T  (BN=128 -> grid 16x16 = 256 blocks, exact CU fill)
    gemm8_kernel<128, 2, 0><<<dim3(16, 16), 512, 0, stream>>>(AO, woT, out, nullptr);
}

// Round 4
// 207.191 us; speedup vs baseline: 1.0080x; 1.0044x over previous
//
#include <hip/hip_runtime.h>
#include <math.h>

// ---------------------------------------------------------------------------
// SlidingWindowGQA: x[2,2048,2048] f32, wq[2048,2048], wk/wv[2048,512], wo[2048,2048]
// out f32 [2,2048,2048].  B=2 S=2048 H=16 KVH=4 D=128 WINDOW=512.
// R4: fixed counted-vmcnt depth (3 half-tiles in flight, gate vmcnt(6)/(5) once
//     per K-tile), lifetime-derived staging stagger, XCD-chunked block swizzle.
// ---------------------------------------------------------------------------

typedef unsigned short u16;
typedef __attribute__((ext_vector_type(4))) float f32x4;
typedef __attribute__((ext_vector_type(8))) __bf16 bf16x8;
typedef __attribute__((ext_vector_type(4))) __bf16 bf16x4;
typedef __attribute__((ext_vector_type(4))) short s16x4;
typedef __attribute__((ext_vector_type(8))) unsigned short u16x8;
typedef __attribute__((ext_vector_type(4))) unsigned short u16x4;

#define DEV static __device__ __forceinline__
#define WAITV(n) asm volatile("s_waitcnt vmcnt(" #n ")" ::: "memory")
#define BAR __builtin_amdgcn_s_barrier()
#define LGKM0 do { asm volatile("s_waitcnt lgkmcnt(0)" ::: "memory"); \
                   __builtin_amdgcn_sched_barrier(0); } while (0)

DEV float bf2f(u16 h) {
    union { unsigned int i; float f; } x;
    x.i = ((unsigned int)h) << 16;
    return x.f;
}
DEV u16 f2bf(float f) {
    union { float f; unsigned int i; } x;
    x.f = f;
    unsigned int u = x.i;
    return (u16)((u + 0x7FFFu + ((u >> 16) & 1u)) >> 16);
}

DEV f32x4 mfma32(bf16x8 a, bf16x8 b, f32x4 c) {
    return __builtin_amdgcn_mfma_f32_16x16x32_bf16(a, b, c, 0, 0, 0);
}
DEV f32x4 mfma16(bf16x4 a, bf16x4 b, f32x4 c) {
#if __has_builtin(__builtin_amdgcn_mfma_f32_16x16x16_bf16)
    return __builtin_amdgcn_mfma_f32_16x16x16_bf16(a, b, c, 0, 0, 0);
#else
    union { bf16x4 v; s16x4 s; } ua, ub;
    ua.v = a; ub.v = b;
    return __builtin_amdgcn_mfma_f32_16x16x16bf16_1k(ua.s, ub.s, c, 0, 0, 0);
#endif
}

DEV void gload_lds16(const void* g, void* lds) {
    __builtin_amdgcn_global_load_lds(
        (const __attribute__((address_space(1))) unsigned int*)g,
        (__attribute__((address_space(3))) unsigned int*)lds, 16, 0, 0);
}

// ---------------------------------------------------------------------------
__global__ __launch_bounds__(256) void sincos_kernel(float* ct, float* st) {
    int idx = blockIdx.x * 256 + threadIdx.x;      // 131072 total
    int s = idx >> 6, d = idx & 63;
    float inv = exp2f(-(float)d * (13.287712379549449f / 64.f));
    float a = (float)s * inv;
    float sv, cv;
    sincosf(a, &sv, &cv);
    ct[idx] = cv;
    st[idx] = sv;
}

__global__ __launch_bounds__(256) void f32_to_bf16_kernel(const float* in, u16* out, int n4) {
    int i = blockIdx.x * 256 + threadIdx.x;
    if (i >= n4) return;
    float4 v = ((const float4*)in)[i];
    u16x4 o;
    o[0] = f2bf(v.x); o[1] = f2bf(v.y); o[2] = f2bf(v.z); o[3] = f2bf(v.w);
    ((u16x4*)out)[i] = o;
}

// Merged weight convert+transpose: 4 matrices, f32 [R][C] -> bf16 [C][R] (ldo=2048)
__global__ __launch_bounds__(256) void convT4_kernel(const float* i0, const float* i1,
                                                     const float* i2, const float* i3,
                                                     u16* o0, u16* o1, u16* o2, u16* o3) {
    __shared__ float tile[32][33];
    int z = blockIdx.z;
    const float* in = (z == 0) ? i0 : (z == 1) ? i1 : (z == 2) ? i2 : i3;
    u16* out = (z == 0) ? o0 : (z == 1) ? o1 : (z == 2) ? o2 : o3;
    int ldi = (z == 1 || z == 2) ? 512 : 2048;
    if ((int)blockIdx.x >= (ldi >> 5)) return;
    int cc = threadIdx.x & 31, rb = threadIdx.x >> 5;
    long r0 = (long)blockIdx.y * 32, c0 = (long)blockIdx.x * 32;
#pragma unroll
    for (int i = 0; i < 4; i++)
        tile[rb + i * 8][cc] = in[(r0 + rb + i * 8) * (long)ldi + c0 + cc];
    __syncthreads();
#pragma unroll
    for (int i = 0; i < 4; i++)
        out[(c0 + rb + i * 8) * 2048L + r0 + cc] = f2bf(tile[cc][rb + i * 8]);
}

// Merged RoPE (Q: 16 heads, K: 4 heads at col offset 2048) on bf16 [4096][3072]
__global__ __launch_bounds__(256) void rope2_kernel(u16* QKV, const float* ct, const float* st) {
    int idx = blockIdx.x * 256 + threadIdx.x;      // 655360 total
    int m, hoff, d0;
    if (idx < 524288) {
        m = idx >> 7;
        int rest = idx & 127;
        hoff = (rest >> 3) * 128;
        d0 = (rest & 7) * 8;
    } else {
        int i2 = idx - 524288;
        m = i2 >> 5;
        int rest = i2 & 31;
        hoff = 2048 + (rest >> 3) * 128;
        d0 = (rest & 7) * 8;
    }
    int s = m & 2047;
    u16* p1 = QKV + (long)m * 3072 + hoff + d0;
    u16* p2 = p1 + 64;
    u16x8 v1 = *(const u16x8*)p1;
    u16x8 v2 = *(const u16x8*)p2;
    const float* cp = ct + s * 64 + d0;
    const float* sp = st + s * 64 + d0;
    u16x8 o1, o2;
#pragma unroll
    for (int j = 0; j < 8; j++) {
        float x1 = bf2f(v1[j]), x2 = bf2f(v2[j]);
        float cc = cp[j], ss = sp[j];
        o1[j] = f2bf(x1 * cc - x2 * ss);
        o2[j] = f2bf(x2 * cc + x1 * ss);
    }
    *(u16x8*)p1 = o1;
    *(u16x8*)p2 = o2;
}

// ---------------------------------------------------------------------------
// 8-phase GEMM: C[M][N] = A[M][2048](bf16,row) * Bt[N][2048](bf16,row)^T.
// BM=256, BK=64 (2 kk-sub-steps of 32), 8 waves, 2-buffer LDS, flat grid with
// XCD-chunked swizzle (GX = tiles along N).
// Phase p reads one C-quadrant's fresh frags and stages ONE half-tile:
//   p0: read Al+Bl, stage Bl(t+1) | p1: read Bh, stage Al(t+2)
//   p2: read Ah,    stage Bh(t+2) | p3: read Bl, stage Ah(t+2)
// Region lifetimes make every staging write race-free (last reader's closing
// barrier precedes the staging phase). ONE gate per tile, before p3's closing
// barrier: vmcnt(6) for BN=256 (5 for BN=128) = "tile t+1 fully landed,
// 3 half-tiles of t+2 in flight". NK-2 gates vmcnt(0); NK-1 un-gated.
// LDS linear in 16B units; global source pre-permuted -> conflict-free.
template <int BN, int WN, int EPI, int GX>
__global__ __launch_bounds__(512, 2) void gemm8_kernel(const u16* __restrict__ A,
                                                       const u16* __restrict__ Bt,
                                                       void* __restrict__ Cout,
                                                       u16* __restrict__ Vt) {
    constexpr int WM = 8 / WN;
    constexpr int MR = 16 / WM;          // A frags per wave
    constexpr int NR = BN / WN / 16;     // B frags per wave
    constexpr int MH = MR / 2, NH = NR / 2;
    constexpr int BSZ = BN * 64;         // B u16 per buffer
    constexpr int BUFSZ = 16384 + BSZ;
    constexpr int NK = 32;               // 2048 / 64

    __shared__ u16 lds[2 * BUFSZ];
    const int tid = threadIdx.x;
    const int w = tid >> 6, l = tid & 63, g = l >> 4, c = l & 15;
    const int wr = w / WN, wc = w % WN;
    // XCD-chunked bijective swizzle (gridDim.x % 8 == 0)
    const int chunk = gridDim.x >> 3;
    const int nid = (blockIdx.x & 7) * chunk + (blockIdx.x >> 3);
    const long m0 = (long)(nid / GX) * 256, n0 = (long)(nid % GX) * BN;

    const int rowS = ((tid >> 6) << 4) | (tid & 15);
    const int ggS = ((tid >> 4) & 3) * 8;

    auto stageA = [&](int t, int h, int j) {
        gload_lds16(A + (size_t)(m0 + h * 128 + rowS) * 2048 + t * 64 + j * 32 + ggS,
                    (void*)&lds[(t & 1) * BUFSZ + h * 8192 + j * 4096 + (tid << 3)]);
    };
    auto stageB = [&](int t, int h, int j) {
        if constexpr (BN == 256) {
            gload_lds16(Bt + (size_t)(n0 + h * 128 + rowS) * 2048 + t * 64 + j * 32 + ggS,
                        (void*)&lds[(t & 1) * BUFSZ + 16384 + h * 8192 + j * 4096 + (tid << 3)]);
        } else {
            gload_lds16(Bt + (size_t)(n0 + h * 64 + (((tid >> 6) & 3) << 4) + (tid & 15)) * 2048
                            + t * 64 + (tid >> 8) * 32 + ggS,
                        (void*)&lds[(t & 1) * BUFSZ + 16384 + h * 4096 + (tid << 3)]);
        }
    };
    auto stageAh = [&](int t, int h) { stageA(t, h, 0); stageA(t, h, 1); };
    auto stageBh = [&](int t, int h) {
        if constexpr (BN == 256) { stageB(t, h, 0); stageB(t, h, 1); }
        else stageB(t, h, 0);
    };

    auto readA = [&](int b, int mi, int kk) -> bf16x8 {
        int rg = wr * MR + mi;
        return *(const bf16x8*)&lds[b * BUFSZ + (rg >> 3) * 8192 + kk * 4096 +
                                    (rg & 7) * 512 + l * 8];
    };
    auto readB = [&](int b, int nj, int kk) -> bf16x8 {
        int rg = wc * NR + nj;
        if constexpr (BN == 256)
            return *(const bf16x8*)&lds[b * BUFSZ + 16384 + (rg >> 3) * 8192 + kk * 4096 +
                                        (rg & 7) * 512 + l * 8];
        else
            return *(const bf16x8*)&lds[b * BUFSZ + 16384 + (rg >> 2) * 4096 + kk * 2048 +
                                        (rg & 3) * 512 + l * 8];
    };

    f32x4 acc[MR][NR];
    const f32x4 zero = {0.f, 0.f, 0.f, 0.f};
#pragma unroll
    for (int i = 0; i < MR; i++)
#pragma unroll
        for (int j = 0; j < NR; j++) acc[i][j] = zero;

    // prologue: all of tile 0, plus Al(1), Bh(1), Ah(1) (3 half-tiles ahead).
    stageAh(0, 0); stageBh(0, 0); stageAh(0, 1); stageBh(0, 1);
    stageAh(1, 0);                 // Al(1)
    stageBh(1, 1);                 // Bh(1)
    stageAh(1, 1);                 // Ah(1)
    if constexpr (BN == 256) WAITV(6); else WAITV(5);   // tile 0 landed
    BAR;

    bf16x8 fa[MH][2], fb[NH][2];

    for (int t = 0; t < NK; ++t) {
        const int b = t & 1;
        // ---- p0: read Al+Bl; stage Bl(t+1)
#pragma unroll
        for (int mi = 0; mi < MH; mi++)
#pragma unroll
            for (int kk = 0; kk < 2; kk++) fa[mi][kk] = readA(b, mi, kk);
#pragma unroll
        for (int nj = 0; nj < NH; nj++)
#pragma unroll
            for (int kk = 0; kk < 2; kk++) fb[nj][kk] = readB(b, nj, kk);
        if (t + 1 < NK) stageBh(t + 1, 0);
        BAR; LGKM0;
        __builtin_amdgcn_s_setprio(1);
#pragma unroll
        for (int mi = 0; mi < MH; mi++)
#pragma unroll
            for (int nj = 0; nj < NH; nj++)
#pragma unroll
                for (int kk = 0; kk < 2; kk++)
                    acc[mi][nj] = mfma32(fa[mi][kk], fb[nj][kk], acc[mi][nj]);
        __builtin_amdgcn_s_setprio(0);
        BAR;
        // ---- p1: read Bh; stage Al(t+2)
#pragma unroll
        for (int nj = 0; nj < NH; nj++)
#pragma unroll
            for (int kk = 0; kk < 2; kk++) fb[nj][kk] = readB(b, NH + nj, kk);
        if (t + 2 < NK) stageAh(t + 2, 0);
        BAR; LGKM0;
        __builtin_amdgcn_s_setprio(1);
#pragma unroll
        for (int mi = 0; mi < MH; mi++)
#pragma unroll
            for (int nj = 0; nj < NH; nj++)
#pragma unroll
                for (int kk = 0; kk < 2; kk++)
                    acc[mi][NH + nj] = mfma32(fa[mi][kk], fb[nj][kk], acc[mi][NH + nj]);
        __builtin_amdgcn_s_setprio(0);
        BAR;
        // ---- p2: read Ah; stage Bh(t+2)
#pragma unroll
        for (int mi = 0; mi < MH; mi++)
#pragma unroll
            for (int kk = 0; kk < 2; kk++) fa[mi][kk] = readA(b, MH + mi, kk);
        if (t + 2 < NK) stageBh(t + 2, 1);
        BAR; LGKM0;
        __builtin_amdgcn_s_setprio(1);
#pragma unroll
        for (int mi = 0; mi < MH; mi++)
#pragma unroll
            for (int nj = 0; nj < NH; nj++)
#pragma unroll
                for (int kk = 0; kk < 2; kk++)
                    acc[MH + mi][NH + nj] = mfma32(fa[mi][kk], fb[nj][kk], acc[MH + mi][NH + nj]);
        __builtin_amdgcn_s_setprio(0);
        BAR;
        // ---- p3: read Bl; stage Ah(t+2); gate
#pragma unroll
        for (int nj = 0; nj < NH; nj++)
#pragma unroll
            for (int kk = 0; kk < 2; kk++) fb[nj][kk] = readB(b, nj, kk);
        if (t + 2 < NK) stageAh(t + 2, 1);
        BAR; LGKM0;
        __builtin_amdgcn_s_setprio(1);
#pragma unroll
        for (int mi = 0; mi < MH; mi++)
#pragma unroll
            for (int nj = 0; nj < NH; nj++)
#pragma unroll
                for (int kk = 0; kk < 2; kk++)
                    acc[MH + mi][nj] = mfma32(fa[mi][kk], fb[nj][kk], acc[MH + mi][nj]);
        __builtin_amdgcn_s_setprio(0);
        if (t <= NK - 3) {
            if constexpr (BN == 256) WAITV(6); else WAITV(5);
        } else if (t == NK - 2) {
            WAITV(0);
        }
        BAR;
    }

    // ---- epilogue ----
    if (EPI == 0) {
        float* C = (float*)Cout;
#pragma unroll
        for (int mi = 0; mi < MR; mi++)
#pragma unroll
            for (int nj = 0; nj < NR; nj++) {
                long row0 = m0 + wr * (256 / WM) + mi * 16 + g * 4;
                long col = n0 + wc * (BN / WN) + nj * 16 + c;
#pragma unroll
                for (int r = 0; r < 4; r++)
                    C[(row0 + r) * 2048 + col] = acc[mi][nj][r];
            }
    } else {
        u16* Cq = (u16*)Cout;
        if (n0 < 2560) {                            // Q/K region -> QKV (ld 3072)
#pragma unroll
            for (int mi = 0; mi < MR; mi++)
#pragma unroll
                for (int nj = 0; nj < NR; nj++) {
                    long row0 = m0 + wr * (256 / WM) + mi * 16 + g * 4;
                    long col = n0 + wc * (BN / WN) + nj * 16 + c;
#pragma unroll
                    for (int r = 0; r < 4; r++)
                        Cq[(row0 + r) * 3072 + col] = f2bf(acc[mi][nj][r]);
                }
        } else {                                    // V region -> Vt transposed
#pragma unroll
            for (int mi = 0; mi < MR; mi++)
#pragma unroll
                for (int nj = 0; nj < NR; nj++) {
                    long row0 = m0 + wr * (256 / WM) + mi * 16 + g * 4;
                    long b = row0 >> 11, s0 = row0 & 2047;
                    long dglob = n0 + wc * (BN / WN) + nj * 16 + c - 2560;
                    u16x4 pk;
                    pk[0] = f2bf(acc[mi][nj][0]); pk[1] = f2bf(acc[mi][nj][1]);
                    pk[2] = f2bf(acc[mi][nj][2]); pk[3] = f2bf(acc[mi][nj][3]);
                    *(u16x4*)&Vt[(b * 512 + dglob) * 2048 + s0] = pk;
                }
        }
    }
}

// ---------------------------------------------------------------------------
// Flash sliding-window GQA (unchanged).
#define ATT_SCALE 0.08838834764831845f
#define L2E 1.4426950408889634f

__global__ __launch_bounds__(256) void attn_kernel(const u16* QKV, const u16* Vt, u16* AO) {
    __shared__ u16 Ks[64 * 128];
    __shared__ u16 Vs[128 * 64];
    const int tid = threadIdx.x;
    const int w = tid >> 6, l = tid & 63, g = l >> 4, c = l & 15;
    const int Tq = blockIdx.x;
    const int h = blockIdx.y;
    const int b = blockIdx.z;
    const int kvh = h >> 2;
    const int q0 = Tq * 64;
    const int qb = q0 + w * 16;

    bf16x8 bq[4];
    {
        const u16* qrow = QKV + (long)(b * 2048 + qb + c) * 3072 + h * 128;
#pragma unroll
        for (int kc = 0; kc < 4; kc++) bq[kc] = *(const bf16x8*)(qrow + kc * 32 + g * 8);
    }

    f32x4 acc_o[8];
    const f32x4 zero = {0.f, 0.f, 0.f, 0.f};
#pragma unroll
    for (int i = 0; i < 8; i++) acc_o[i] = zero;
    float m_run = -3.0e38f, l_run = 0.f;

    const int t_lo = (q0 > 511) ? ((q0 - 511) >> 6) : 0;
    const int t_hi = Tq;

    for (int t = t_lo; t <= t_hi; ++t) {
        const int kv0 = t * 64;
#pragma unroll
        for (int i = 0; i < 4; i++) {
            int o = (i * 256 + tid) * 16;
            int key = o >> 8;
            int cl = ((o >> 4) & 15) ^ (key & 15);
            gload_lds16(QKV + (long)(b * 2048 + kv0 + key) * 3072 + 2048 + kvh * 128 + cl * 8,
                        (void*)&Ks[(i * 256 + w * 64) * 8]);
        }
#pragma unroll
        for (int i = 0; i < 4; i++) {
            int o = (i * 256 + tid) * 16;
            int d = o >> 7;
            int cl = ((o >> 4) & 7) ^ (d & 7);
            gload_lds16(Vt + (long)((b * 4 + kvh) * 128 + d) * 2048 + kv0 + cl * 8,
                        (void*)&Vs[(i * 256 + w * 64) * 8]);
        }
        __syncthreads();

        f32x4 sacc[4];
#pragma unroll
        for (int n = 0; n < 4; n++) {
            sacc[n] = zero;
#pragma unroll
            for (int kc = 0; kc < 4; kc++) {
                int row = n * 16 + c;
                int ch = (kc * 4 + g) ^ c;
                bf16x8 kf = *(const bf16x8*)&Ks[row * 128 + ch * 8];
                sacc[n] = mfma32(kf, bq[kc], sacc[n]);
            }
        }

        const bool edge = (kv0 + 63 > qb) || (kv0 < qb + 15 - 511);
        float p[4][4];
        float m_tile = -3.0e38f;
#pragma unroll
        for (int n = 0; n < 4; n++)
#pragma unroll
            for (int r = 0; r < 4; r++) {
                float s = sacc[n][r] * ATT_SCALE;
                if (edge) {
                    int j = kv0 + n * 16 + 4 * g + r;
                    int q = qb + c;
                    if (j > q || j < q - 511) s = -__builtin_inff();
                }
                p[n][r] = s;
                m_tile = fmaxf(m_tile, s);
            }
        m_tile = fmaxf(m_tile, __shfl_xor(m_tile, 16));
        m_tile = fmaxf(m_tile, __shfl_xor(m_tile, 32));
        float m_new = fmaxf(m_run, m_tile);
        float alpha = exp2f((m_run - m_new) * L2E);
        float lsum = 0.f;
#pragma unroll
        for (int n = 0; n < 4; n++)
#pragma unroll
            for (int r = 0; r < 4; r++) {
                float e = exp2f((p[n][r] - m_new) * L2E);
                p[n][r] = e;
                lsum += e;
            }
        lsum += __shfl_xor(lsum, 16);
        lsum += __shfl_xor(lsum, 32);
        l_run = l_run * alpha + lsum;
        m_run = m_new;

        float alpha_r[4];
#pragma unroll
        for (int r = 0; r < 4; r++) alpha_r[r] = __shfl(alpha, (g << 4) + 4 * g + r);
#pragma unroll
        for (int dn = 0; dn < 8; dn++) {
            f32x4 t2 = acc_o[dn];
            t2[0] *= alpha_r[0]; t2[1] *= alpha_r[1];
            t2[2] *= alpha_r[2]; t2[3] *= alpha_r[3];
            acc_o[dn] = t2;
        }

        bf16x4 ap[4];
#pragma unroll
        for (int n = 0; n < 4; n++) {
            union { u16x4 u; bf16x4 b; } pk;
            pk.u[0] = f2bf(p[n][0]); pk.u[1] = f2bf(p[n][1]);
            pk.u[2] = f2bf(p[n][2]); pk.u[3] = f2bf(p[n][3]);
            ap[n] = pk.b;
        }

#pragma unroll
        for (int n = 0; n < 4; n++)
#pragma unroll
            for (int dn = 0; dn < 8; dn++) {
                int row = dn * 16 + c;
                int ch = (2 * n + (g >> 1)) ^ (c & 7);
                bf16x4 vf = *(const bf16x4*)&Vs[row * 64 + ch * 8 + (g & 1) * 4];
                acc_o[dn] = mfma16(ap[n], vf, acc_o[dn]);
            }
        __syncthreads();
    }

    float lr[4];
#pragma unroll
    for (int r = 0; r < 4; r++) {
        float lq = __shfl(l_run, (g << 4) + 4 * g + r);
        lr[r] = 1.f / lq;
    }
#pragma unroll
    for (int dn = 0; dn < 8; dn++)
#pragma unroll
        for (int r = 0; r < 4; r++) {
            long row = (long)(b * 2048 + qb + 4 * g + r);
            AO[row * 2048 + h * 128 + dn * 16 + c] = f2bf(acc_o[dn][r] * lr[r]);
        }
}

// ---------------------------------------------------------------------------
extern "C" void kernel_launch(void* const* d_in, const int* in_sizes, int n_in,
                              void* d_out, int out_size, void* d_ws, size_t ws_size,
                              hipStream_t stream) {
    const float* x = (const float*)d_in[0];
    const float* wq = (const float*)d_in[1];
    const float* wk = (const float*)d_in[2];
    const float* wv = (const float*)d_in[3];
    const float* wo = (const float*)d_in[4];
    float* out = (float*)d_out;

    char* ws = (char*)d_ws;
    u16* xb = (u16*)(ws);                         // [4096][2048]        16.78 MB
    u16* wAll = (u16*)(ws + 16777216);            // [3072][2048] (BT)   12.58 MB
    u16* woT = (u16*)(ws + 29360128);             // [2048][2048] (BT)    8.39 MB
    u16* QKV = (u16*)(ws + 37748736);             // [4096][3072]        25.17 MB
    u16* Vt = (u16*)(ws + 62914560);              // [1024][2048]         4.19 MB
    u16* AO = (u16*)(ws + 67108864);              // [4096][2048]        16.78 MB
    float* ct = (float*)(ws + 83886080);          // [2048][64]
    float* st = (float*)(ws + 84410368);          // [2048][64]

    sincos_kernel<<<512, 256, 0, stream>>>(ct, st);
    f32_to_bf16_kernel<<<8192, 256, 0, stream>>>(x, xb, 2097152);
    convT4_kernel<<<dim3(64, 64, 4), 256, 0, stream>>>(
        wq, wk, wv, wo, wAll, wAll + (long)2048 * 2048, wAll + (long)2560 * 2048, woT);

    // QKV = xb @ wAll^T (V columns written transposed into Vt); 192 blocks (GX=12)
    gemm8_kernel<256, 4, 1, 12><<<192, 512, 0, stream>>>(xb, wAll, QKV, Vt);

    rope2_kernel<<<2560, 256, 0, stream>>>(QKV, ct, st);

    attn_kernel<<<dim3(32, 16, 2), 256, 0, stream>>>(QKV, Vt, AO);

    // out = AO @ woT^T; 256 blocks (GX=16), exact CU fill
    gemm8_kernel<128, 2, 0, 16><<<256, 512, 0, stream>>>(AO, woT, out, nullptr);
}

// Round 7
// 204.645 us; speedup vs baseline: 1.0206x; 1.0124x over previous
//
#include <hip/hip_runtime.h>
#include <math.h>

// ---------------------------------------------------------------------------
// SlidingWindowGQA: x[2,2048,2048] f32, wq[2048,2048], wk/wv[2048,512], wo[2048,2048]
// out f32 [2,2048,2048].  B=2 S=2048 H=16 KVH=4 D=128 WINDOW=512.
// R7: back to the PROVEN R1 GEMM structure (counted-vmcnt schedules abandoned:
//     R2-R6 showed they race on HW despite passing paper audits). New safe wins:
//     attn double-buffered (stage-first + one barrier/tile, R1-GEMM discipline),
//     8-wave attn blocks (halve staging + blocks), V-transpose fused in QKV
//     epilogue, prep passes fused into one launch.
// ---------------------------------------------------------------------------

typedef unsigned short u16;
typedef __attribute__((ext_vector_type(4))) float f32x4;
typedef __attribute__((ext_vector_type(8))) __bf16 bf16x8;
typedef __attribute__((ext_vector_type(4))) __bf16 bf16x4;
typedef __attribute__((ext_vector_type(4))) short s16x4;
typedef __attribute__((ext_vector_type(8))) unsigned short u16x8;
typedef __attribute__((ext_vector_type(4))) unsigned short u16x4;

#define DEV static __device__ __forceinline__

DEV float bf2f(u16 h) {
    union { unsigned int i; float f; } x;
    x.i = ((unsigned int)h) << 16;
    return x.f;
}
DEV u16 f2bf(float f) {
    union { float f; unsigned int i; } x;
    x.f = f;
    unsigned int u = x.i;
    return (u16)((u + 0x7FFFu + ((u >> 16) & 1u)) >> 16);
}

DEV f32x4 mfma32(bf16x8 a, bf16x8 b, f32x4 c) {
    return __builtin_amdgcn_mfma_f32_16x16x32_bf16(a, b, c, 0, 0, 0);
}
DEV f32x4 mfma16(bf16x4 a, bf16x4 b, f32x4 c) {
#if __has_builtin(__builtin_amdgcn_mfma_f32_16x16x16_bf16)
    return __builtin_amdgcn_mfma_f32_16x16x16_bf16(a, b, c, 0, 0, 0);
#else
    union { bf16x4 v; s16x4 s; } ua, ub;
    ua.v = a; ub.v = b;
    return __builtin_amdgcn_mfma_f32_16x16x16bf16_1k(ua.s, ub.s, c, 0, 0, 0);
#endif
}

DEV void gload_lds16(const void* g, void* lds) {
    __builtin_amdgcn_global_load_lds(
        (const __attribute__((address_space(1))) unsigned int*)g,
        (__attribute__((address_space(3))) unsigned int*)lds, 16, 0, 0);
}

// ---------------------------------------------------------------------------
// Fused prep: sincos table + x->bf16 cast + 4x weight convert/transpose.
// Flat grid 18944 blocks x 256 thr:
//   [0,512):        sincos ct/st [2048][64]
//   [512,8704):     f32->bf16 cast of x (float4/thread)
//   [8704,18944):   convT of wq(4096) | wk(1024) | wv(1024) | wo(4096)
__global__ __launch_bounds__(256) void prep_kernel(const float* x, const float* wq,
                                                   const float* wk, const float* wv,
                                                   const float* wo, u16* xb, u16* wAll,
                                                   u16* woT, float* ct, float* st) {
    __shared__ float tile[32][33];
    const int bid = blockIdx.x;
    const int tid = threadIdx.x;
    if (bid < 512) {
        int idx = bid * 256 + tid;                 // 131072
        int s = idx >> 6, d = idx & 63;
        float inv = exp2f(-(float)d * (13.287712379549449f / 64.f));
        float a = (float)s * inv;
        float sv, cv;
        sincosf(a, &sv, &cv);
        ct[idx] = cv;
        st[idx] = sv;
        return;
    }
    if (bid < 8704) {
        int i = (bid - 512) * 256 + tid;           // 2097152 float4s
        float4 v = ((const float4*)x)[i];
        u16x4 o;
        o[0] = f2bf(v.x); o[1] = f2bf(v.y); o[2] = f2bf(v.z); o[3] = f2bf(v.w);
        ((u16x4*)xb)[i] = o;
        return;
    }
    // convT: f32 [R][C](ldi) -> bf16 [C][R](ld 2048)
    int r = bid - 8704;
    const float* in;
    u16* out;
    int ldi, bx, by;
    if (r < 4096) { in = wq; out = wAll; ldi = 2048; bx = r & 63; by = r >> 6; }
    else if (r < 5120) { r -= 4096; in = wk; out = wAll + (long)2048 * 2048; ldi = 512; bx = r & 15; by = r >> 4; }
    else if (r < 6144) { r -= 5120; in = wv; out = wAll + (long)2560 * 2048; ldi = 512; bx = r & 15; by = r >> 4; }
    else { r -= 6144; in = wo; out = woT; ldi = 2048; bx = r & 63; by = r >> 6; }
    int cc = tid & 31, rb = tid >> 5;
    long r0 = (long)by * 32, c0 = (long)bx * 32;
#pragma unroll
    for (int i = 0; i < 4; i++)
        tile[rb + i * 8][cc] = in[(r0 + rb + i * 8) * (long)ldi + c0 + cc];
    __syncthreads();
#pragma unroll
    for (int i = 0; i < 4; i++)
        out[(c0 + rb + i * 8) * 2048L + r0 + cc] = f2bf(tile[cc][rb + i * 8]);
}

// Merged RoPE (Q: 16 heads, K: 4 heads at col offset 2048) on bf16 [4096][3072]
__global__ __launch_bounds__(256) void rope2_kernel(u16* QKV, const float* ct, const float* st) {
    int idx = blockIdx.x * 256 + threadIdx.x;      // 655360 total
    int m, hoff, d0;
    if (idx < 524288) {
        m = idx >> 7;
        int rest = idx & 127;
        hoff = (rest >> 3) * 128;
        d0 = (rest & 7) * 8;
    } else {
        int i2 = idx - 524288;
        m = i2 >> 5;
        int rest = i2 & 31;
        hoff = 2048 + (rest >> 3) * 128;
        d0 = (rest & 7) * 8;
    }
    int s = m & 2047;
    u16* p1 = QKV + (long)m * 3072 + hoff + d0;
    u16* p2 = p1 + 64;
    u16x8 v1 = *(const u16x8*)p1;
    u16x8 v2 = *(const u16x8*)p2;
    const float* cp = ct + s * 64 + d0;
    const float* sp = st + s * 64 + d0;
    u16x8 o1, o2;
#pragma unroll
    for (int j = 0; j < 8; j++) {
        float x1 = bf2f(v1[j]), x2 = bf2f(v2[j]);
        float cc = cp[j], ss = sp[j];
        o1[j] = f2bf(x1 * cc - x2 * ss);
        o2[j] = f2bf(x2 * cc + x1 * ss);
    }
    *(u16x8*)p1 = o1;
    *(u16x8*)p2 = o2;
}

// ---------------------------------------------------------------------------
// GEMM (R1-proven structure): C[M][N] = A[M][K](bf16,row) * Bt[N][K](bf16,row)^T.
// 128x128 tile, BK=32, 4 waves (2x2), double-buffered LDS, global_load_lds(16B),
// XOR swizzle chunk^=((row>>1)&3) -> 2-way (free) ds_read_b128 conflicts.
// Stage-first + ONE __syncthreads per K-tile (compiler drains vmcnt at barrier).
// EPI: 0 = f32 out; 1 = QKV bf16 (ld 3072), V cols (n0>=2560) transposed to Vt.
template <int EPI>
__global__ __launch_bounds__(256) void gemm_bt_kernel(const u16* A, const u16* Bt, void* Cout,
                                                      u16* Vt, int M, int N, int K) {
    __shared__ u16 As[2][128 * 32];
    __shared__ u16 Bs[2][128 * 32];
    const int tid = threadIdx.x;
    const int w = tid >> 6, l = tid & 63, g = l >> 4, c = l & 15;
    const int wm = w >> 1, wn = w & 1;
    const long m0 = (long)blockIdx.y * 128, n0 = (long)blockIdx.x * 128;
    const int nk = K >> 5;

    f32x4 acc[4][4];
    const f32x4 zero = {0.f, 0.f, 0.f, 0.f};
#pragma unroll
    for (int i = 0; i < 4; i++)
#pragma unroll
        for (int j = 0; j < 4; j++) acc[i][j] = zero;

    auto stage = [&](int buf, int kt) {
#pragma unroll
        for (int i = 0; i < 2; i++) {
            int o = (i * 256 + tid) * 16;
            int row = o >> 6;
            int cl = ((o >> 4) & 3) ^ ((row >> 1) & 3);
            gload_lds16(A + (m0 + row) * (long)K + kt * 32 + cl * 8,
                        (void*)&As[buf][(i * 256 + w * 64) * 8]);
        }
#pragma unroll
        for (int i = 0; i < 2; i++) {
            int o = (i * 256 + tid) * 16;
            int row = o >> 6;
            int cl = ((o >> 4) & 3) ^ ((row >> 1) & 3);
            gload_lds16(Bt + (n0 + row) * (long)K + kt * 32 + cl * 8,
                        (void*)&Bs[buf][(i * 256 + w * 64) * 8]);
        }
    };

    stage(0, 0);
    __syncthreads();
    int buf = 0;
    for (int kt = 0; kt < nk; ++kt) {
        if (kt + 1 < nk) stage(buf ^ 1, kt + 1);
        bf16x8 af[4], bf[4];
#pragma unroll
        for (int i = 0; i < 4; i++) {
            int rowa = wm * 64 + i * 16 + c;
            int cha = g ^ ((rowa >> 1) & 3);
            af[i] = *(const bf16x8*)&As[buf][rowa * 32 + cha * 8];
            int rowb = wn * 64 + i * 16 + c;
            int chb = g ^ ((rowb >> 1) & 3);
            bf[i] = *(const bf16x8*)&Bs[buf][rowb * 32 + chb * 8];
        }
#pragma unroll
        for (int i = 0; i < 4; i++)
#pragma unroll
            for (int j = 0; j < 4; j++) acc[i][j] = mfma32(af[i], bf[j], acc[i][j]);
        __syncthreads();
        buf ^= 1;
    }

    // ---- epilogue ----
    if (EPI == 0) {
        float* C = (float*)Cout;
#pragma unroll
        for (int i = 0; i < 4; i++)
#pragma unroll
            for (int j = 0; j < 4; j++) {
                long row0 = m0 + wm * 64 + i * 16 + g * 4;
                long col = n0 + wn * 64 + j * 16 + c;
#pragma unroll
                for (int r = 0; r < 4; r++)
                    C[(row0 + r) * (long)N + col] = acc[i][j][r];
            }
    } else {
        u16* Cq = (u16*)Cout;
        if (n0 < 2560) {                            // Q/K region -> QKV (ld 3072)
#pragma unroll
            for (int i = 0; i < 4; i++)
#pragma unroll
                for (int j = 0; j < 4; j++) {
                    long row0 = m0 + wm * 64 + i * 16 + g * 4;
                    long col = n0 + wn * 64 + j * 16 + c;
#pragma unroll
                    for (int r = 0; r < 4; r++)
                        Cq[(row0 + r) * 3072 + col] = f2bf(acc[i][j][r]);
                }
        } else {                                    // V region -> Vt transposed
#pragma unroll
            for (int i = 0; i < 4; i++)
#pragma unroll
                for (int j = 0; j < 4; j++) {
                    long row0 = m0 + wm * 64 + i * 16 + g * 4;
                    long bb = row0 >> 11, s0 = row0 & 2047;
                    long dglob = n0 + wn * 64 + j * 16 + c - 2560;
                    u16x4 pk;
                    pk[0] = f2bf(acc[i][j][0]); pk[1] = f2bf(acc[i][j][1]);
                    pk[2] = f2bf(acc[i][j][2]); pk[3] = f2bf(acc[i][j][3]);
                    *(u16x4*)&Vt[(bb * 512 + dglob) * 2048 + s0] = pk;
                }
        }
    }
}

// ---------------------------------------------------------------------------
// Flash sliding-window GQA, double-buffered (stage-first + 1 barrier/tile).
// Block: 512 thr = 8 waves; (q-tile of 128, h, b). Wave owns 16 q-rows.
// Swapped QK^T: S^T = mfma32(K_frag, Q^T_frag) -> lane holds q=lane&15 columns;
// S^T D-layout == 16x16x16 A-layout: P feeds PV with no cross-lane movement.
// K LDS [64][128] swz chunk^=(row&15); V^T LDS [128][64] swz chunk^=(row&7).
// Per-wave `active` gating skips masked-out tiles' compute (all waves barrier).
#define ATT_SCALE 0.08838834764831845f
#define L2E 1.4426950408889634f

__global__ __launch_bounds__(512) void attn_kernel(const u16* QKV, const u16* Vt, u16* AO) {
    __shared__ u16 Ks[2][64 * 128];
    __shared__ u16 Vs[2][128 * 64];
    const int tid = threadIdx.x;
    const int w = tid >> 6, l = tid & 63, g = l >> 4, c = l & 15;
    const int h = blockIdx.y;
    const int b = blockIdx.z;
    const int kvh = h >> 2;
    const int q0 = blockIdx.x * 128;
    const int qb = q0 + w * 16;

    bf16x8 bq[4];
    {
        const u16* qrow = QKV + (long)(b * 2048 + qb + c) * 3072 + h * 128;
#pragma unroll
        for (int kc = 0; kc < 4; kc++) bq[kc] = *(const bf16x8*)(qrow + kc * 32 + g * 8);
    }

    f32x4 acc_o[8];
    const f32x4 zero = {0.f, 0.f, 0.f, 0.f};
#pragma unroll
    for (int i = 0; i < 8; i++) acc_o[i] = zero;
    float m_run = -3.0e38f, l_run = 0.f;

    const int t_lo = (q0 > 511) ? ((q0 - 511) >> 6) : 0;
    const int t_hi = (q0 + 127) >> 6;

    auto stage = [&](int sb, int t) {
        const int kv0 = t * 64;
#pragma unroll
        for (int i = 0; i < 2; i++) {
            int o = (i * 512 + tid) * 16;
            int key = o >> 8;
            int cl = ((o >> 4) & 15) ^ (key & 15);
            gload_lds16(QKV + (long)(b * 2048 + kv0 + key) * 3072 + 2048 + kvh * 128 + cl * 8,
                        (void*)&Ks[sb][(i * 512 + w * 64) * 8]);
        }
#pragma unroll
        for (int i = 0; i < 2; i++) {
            int o = (i * 512 + tid) * 16;
            int d = o >> 7;
            int cl = ((o >> 4) & 7) ^ (d & 7);
            gload_lds16(Vt + (long)((b * 4 + kvh) * 128 + d) * 2048 + kv0 + cl * 8,
                        (void*)&Vs[sb][(i * 512 + w * 64) * 8]);
        }
    };

    stage(0, t_lo);
    __syncthreads();
    int buf = 0;

    for (int t = t_lo; t <= t_hi; ++t) {
        const int kv0 = t * 64;
        if (t < t_hi) stage(buf ^ 1, t + 1);       // overlap with compute below

        const bool active = (kv0 <= qb + 15) && (kv0 + 63 >= qb - 511);
        if (active) {
            f32x4 sacc[4];
#pragma unroll
            for (int n = 0; n < 4; n++) {
                sacc[n] = zero;
#pragma unroll
                for (int kc = 0; kc < 4; kc++) {
                    int row = n * 16 + c;
                    int ch = (kc * 4 + g) ^ c;
                    bf16x8 kf = *(const bf16x8*)&Ks[buf][row * 128 + ch * 8];
                    sacc[n] = mfma32(kf, bq[kc], sacc[n]);
                }
            }

            const bool edge = (kv0 + 63 > qb) || (kv0 < qb + 15 - 511);
            float p[4][4];
            float m_tile = -3.0e38f;
#pragma unroll
            for (int n = 0; n < 4; n++)
#pragma unroll
                for (int r = 0; r < 4; r++) {
                    float s = sacc[n][r] * ATT_SCALE;
                    if (edge) {
                        int j = kv0 + n * 16 + 4 * g + r;
                        int q = qb + c;
                        if (j > q || j < q - 511) s = -__builtin_inff();
                    }
                    p[n][r] = s;
                    m_tile = fmaxf(m_tile, s);
                }
            m_tile = fmaxf(m_tile, __shfl_xor(m_tile, 16));
            m_tile = fmaxf(m_tile, __shfl_xor(m_tile, 32));
            float m_new = fmaxf(m_run, m_tile);
            float alpha = exp2f((m_run - m_new) * L2E);
            float lsum = 0.f;
#pragma unroll
            for (int n = 0; n < 4; n++)
#pragma unroll
                for (int r = 0; r < 4; r++) {
                    float e = exp2f((p[n][r] - m_new) * L2E);
                    p[n][r] = e;
                    lsum += e;
                }
            lsum += __shfl_xor(lsum, 16);
            lsum += __shfl_xor(lsum, 32);
            l_run = l_run * alpha + lsum;
            m_run = m_new;

            float alpha_r[4];
#pragma unroll
            for (int r = 0; r < 4; r++) alpha_r[r] = __shfl(alpha, (g << 4) + 4 * g + r);
#pragma unroll
            for (int dn = 0; dn < 8; dn++) {
                f32x4 t2 = acc_o[dn];
                t2[0] *= alpha_r[0]; t2[1] *= alpha_r[1];
                t2[2] *= alpha_r[2]; t2[3] *= alpha_r[3];
                acc_o[dn] = t2;
            }

            bf16x4 ap[4];
#pragma unroll
            for (int n = 0; n < 4; n++) {
                union { u16x4 u; bf16x4 b; } pk;
                pk.u[0] = f2bf(p[n][0]); pk.u[1] = f2bf(p[n][1]);
                pk.u[2] = f2bf(p[n][2]); pk.u[3] = f2bf(p[n][3]);
                ap[n] = pk.b;
            }

#pragma unroll
            for (int n = 0; n < 4; n++)
#pragma unroll
                for (int dn = 0; dn < 8; dn++) {
                    int row = dn * 16 + c;
                    int ch = (2 * n + (g >> 1)) ^ (c & 7);
                    bf16x4 vf = *(const bf16x4*)&Vs[buf][row * 64 + ch * 8 + (g & 1) * 4];
                    acc_o[dn] = mfma16(ap[n], vf, acc_o[dn]);
                }
        }
        __syncthreads();                            // drains stage(t+1) + reads
        buf ^= 1;
    }

    float lr[4];
#pragma unroll
    for (int r = 0; r < 4; r++) {
        float lq = __shfl(l_run, (g << 4) + 4 * g + r);
        lr[r] = 1.f / lq;
    }
#pragma unroll
    for (int dn = 0; dn < 8; dn++)
#pragma unroll
        for (int r = 0; r < 4; r++) {
            long row = (long)(b * 2048 + qb + 4 * g + r);
            AO[row * 2048 + h * 128 + dn * 16 + c] = f2bf(acc_o[dn][r] * lr[r]);
        }
}

// ---------------------------------------------------------------------------
extern "C" void kernel_launch(void* const* d_in, const int* in_sizes, int n_in,
                              void* d_out, int out_size, void* d_ws, size_t ws_size,
                              hipStream_t stream) {
    const float* x = (const float*)d_in[0];
    const float* wq = (const float*)d_in[1];
    const float* wk = (const float*)d_in[2];
    const float* wv = (const float*)d_in[3];
    const float* wo = (const float*)d_in[4];
    float* out = (float*)d_out;

    char* ws = (char*)d_ws;
    u16* xb = (u16*)(ws);                         // [4096][2048]        16.78 MB
    u16* wAll = (u16*)(ws + 16777216);            // [3072][2048] (BT)   12.58 MB
    u16* woT = (u16*)(ws + 29360128);             // [2048][2048] (BT)    8.39 MB
    u16* QKV = (u16*)(ws + 37748736);             // [4096][3072]        25.17 MB
    u16* Vt = (u16*)(ws + 62914560);              // [1024][2048]         4.19 MB
    u16* AO = (u16*)(ws + 67108864);              // [4096][2048]        16.78 MB
    float* ct = (float*)(ws + 83886080);          // [2048][64]
    float* st = (float*)(ws + 84410368);          // [2048][64]

    prep_kernel<<<18944, 256, 0, stream>>>(x, wq, wk, wv, wo, xb, wAll, woT, ct, st);

    // QKV = xb @ wAll^T (V columns written transposed into Vt)
    gemm_bt_kernel<1><<<dim3(24, 32), 256, 0, stream>>>(xb, wAll, QKV, Vt, 4096, 3072, 2048);

    rope2_kernel<<<2560, 256, 0, stream>>>(QKV, ct, st);

    attn_kernel<<<dim3(16, 16, 2), 512, 0, stream>>>(QKV, Vt, AO);

    // out = AO @ woT^T
    gemm_bt_kernel<0><<<dim3(16, 32), 256, 0, stream>>>(AO, woT, out, nullptr, 4096, 2048, 2048);
}

// Round 8
// 182.105 us; speedup vs baseline: 1.1469x; 1.1238x over previous
//
#include <hip/hip_runtime.h>
#include <math.h>

// ---------------------------------------------------------------------------
// SlidingWindowGQA: x[2,2048,2048] f32, wq[2048,2048], wk/wv[2048,512], wo[2048,2048]
// out f32 [2,2048,2048].  B=2 S=2048 H=16 KVH=4 D=128 WINDOW=512.
// R8: GEMM reverted byte-identical to R1 (72 VGPR / 70 us proven; R7's fused
//     V-transpose epilogue pushed VGPR 72->108, occupancy 28.8->16.8%, 94 us).
//     Separate V-transpose kernel restored. Keep R7 prep fusion + 8-wave
//     double-buffered attention.
// ---------------------------------------------------------------------------

typedef unsigned short u16;
typedef __attribute__((ext_vector_type(4))) float f32x4;
typedef __attribute__((ext_vector_type(8))) __bf16 bf16x8;
typedef __attribute__((ext_vector_type(4))) __bf16 bf16x4;
typedef __attribute__((ext_vector_type(4))) short s16x4;
typedef __attribute__((ext_vector_type(8))) unsigned short u16x8;
typedef __attribute__((ext_vector_type(4))) unsigned short u16x4;

#define DEV static __device__ __forceinline__

DEV float bf2f(u16 h) {
    union { unsigned int i; float f; } x;
    x.i = ((unsigned int)h) << 16;
    return x.f;
}
DEV u16 f2bf(float f) {
    union { float f; unsigned int i; } x;
    x.f = f;
    unsigned int u = x.i;
    return (u16)((u + 0x7FFFu + ((u >> 16) & 1u)) >> 16);
}

DEV f32x4 mfma32(bf16x8 a, bf16x8 b, f32x4 c) {
    return __builtin_amdgcn_mfma_f32_16x16x32_bf16(a, b, c, 0, 0, 0);
}
DEV f32x4 mfma16(bf16x4 a, bf16x4 b, f32x4 c) {
#if __has_builtin(__builtin_amdgcn_mfma_f32_16x16x16_bf16)
    return __builtin_amdgcn_mfma_f32_16x16x16_bf16(a, b, c, 0, 0, 0);
#else
    union { bf16x4 v; s16x4 s; } ua, ub;
    ua.v = a; ub.v = b;
    return __builtin_amdgcn_mfma_f32_16x16x16bf16_1k(ua.s, ub.s, c, 0, 0, 0);
#endif
}

DEV void gload_lds16(const void* g, void* lds) {
    __builtin_amdgcn_global_load_lds(
        (const __attribute__((address_space(1))) unsigned int*)g,
        (__attribute__((address_space(3))) unsigned int*)lds, 16, 0, 0);
}

// ---------------------------------------------------------------------------
// Fused prep: sincos table + x->bf16 cast + 4x weight convert/transpose.
__global__ __launch_bounds__(256) void prep_kernel(const float* x, const float* wq,
                                                   const float* wk, const float* wv,
                                                   const float* wo, u16* xb, u16* wAll,
                                                   u16* woT, float* ct, float* st) {
    __shared__ float tile[32][33];
    const int bid = blockIdx.x;
    const int tid = threadIdx.x;
    if (bid < 512) {
        int idx = bid * 256 + tid;                 // 131072
        int s = idx >> 6, d = idx & 63;
        float inv = exp2f(-(float)d * (13.287712379549449f / 64.f));
        float a = (float)s * inv;
        float sv, cv;
        sincosf(a, &sv, &cv);
        ct[idx] = cv;
        st[idx] = sv;
        return;
    }
    if (bid < 8704) {
        int i = (bid - 512) * 256 + tid;           // 2097152 float4s
        float4 v = ((const float4*)x)[i];
        u16x4 o;
        o[0] = f2bf(v.x); o[1] = f2bf(v.y); o[2] = f2bf(v.z); o[3] = f2bf(v.w);
        ((u16x4*)xb)[i] = o;
        return;
    }
    // convT: f32 [R][C](ldi) -> bf16 [C][R](ld 2048)
    int r = bid - 8704;
    const float* in;
    u16* out;
    int ldi, bx, by;
    if (r < 4096) { in = wq; out = wAll; ldi = 2048; bx = r & 63; by = r >> 6; }
    else if (r < 5120) { r -= 4096; in = wk; out = wAll + (long)2048 * 2048; ldi = 512; bx = r & 15; by = r >> 4; }
    else if (r < 6144) { r -= 5120; in = wv; out = wAll + (long)2560 * 2048; ldi = 512; bx = r & 15; by = r >> 4; }
    else { r -= 6144; in = wo; out = woT; ldi = 2048; bx = r & 63; by = r >> 6; }
    int cc = tid & 31, rb = tid >> 5;
    long r0 = (long)by * 32, c0 = (long)bx * 32;
#pragma unroll
    for (int i = 0; i < 4; i++)
        tile[rb + i * 8][cc] = in[(r0 + rb + i * 8) * (long)ldi + c0 + cc];
    __syncthreads();
#pragma unroll
    for (int i = 0; i < 4; i++)
        out[(c0 + rb + i * 8) * 2048L + r0 + cc] = f2bf(tile[cc][rb + i * 8]);
}

// bf16 [R][C] -> bf16 [C][R], batched (R1-proven)
__global__ __launch_bounds__(256) void transpose_bf16_kernel(const u16* in, int ldi, long in_bs,
                                                             u16* out, int ldo, long out_bs) {
    __shared__ u16 tile[32][33];
    in += (long)blockIdx.z * in_bs;
    out += (long)blockIdx.z * out_bs;
    int cc = threadIdx.x & 31, rb = threadIdx.x >> 5;
    long r0 = (long)blockIdx.y * 32, c0 = (long)blockIdx.x * 32;
#pragma unroll
    for (int i = 0; i < 4; i++)
        tile[rb + i * 8][cc] = in[(r0 + rb + i * 8) * (long)ldi + c0 + cc];
    __syncthreads();
#pragma unroll
    for (int i = 0; i < 4; i++)
        out[(c0 + rb + i * 8) * (long)ldo + r0 + cc] = tile[cc][rb + i * 8];
}

// Merged RoPE (Q: 16 heads, K: 4 heads at col offset 2048) on bf16 [4096][3072]
__global__ __launch_bounds__(256) void rope2_kernel(u16* QKV, const float* ct, const float* st) {
    int idx = blockIdx.x * 256 + threadIdx.x;      // 655360 total
    int m, hoff, d0;
    if (idx < 524288) {
        m = idx >> 7;
        int rest = idx & 127;
        hoff = (rest >> 3) * 128;
        d0 = (rest & 7) * 8;
    } else {
        int i2 = idx - 524288;
        m = i2 >> 5;
        int rest = i2 & 31;
        hoff = 2048 + (rest >> 3) * 128;
        d0 = (rest & 7) * 8;
    }
    int s = m & 2047;
    u16* p1 = QKV + (long)m * 3072 + hoff + d0;
    u16* p2 = p1 + 64;
    u16x8 v1 = *(const u16x8*)p1;
    u16x8 v2 = *(const u16x8*)p2;
    const float* cp = ct + s * 64 + d0;
    const float* sp = st + s * 64 + d0;
    u16x8 o1, o2;
#pragma unroll
    for (int j = 0; j < 8; j++) {
        float x1 = bf2f(v1[j]), x2 = bf2f(v2[j]);
        float cc = cp[j], ss = sp[j];
        o1[j] = f2bf(x1 * cc - x2 * ss);
        o2[j] = f2bf(x2 * cc + x1 * ss);
    }
    *(u16x8*)p1 = o1;
    *(u16x8*)p2 = o2;
}

// ---------------------------------------------------------------------------
// GEMM (R1 byte-identical): C[M][N] = A[M][K](bf16,row) * Bt[N][K](bf16,row)^T.
// 128x128 tile, BK=32, 4 waves (2x2), double-buffered LDS, global_load_lds(16B),
// XOR swizzle chunk^=((row>>1)&3) -> 2-way (free) ds_read_b128 conflicts.
template <bool OUT_BF16>
__global__ __launch_bounds__(256) void gemm_bt_kernel(const u16* A, const u16* Bt, void* Cout,
                                                      int M, int N, int K) {
    __shared__ u16 As[2][128 * 32];
    __shared__ u16 Bs[2][128 * 32];
    const int tid = threadIdx.x;
    const int w = tid >> 6, l = tid & 63, g = l >> 4, c = l & 15;
    const int wm = w >> 1, wn = w & 1;
    const long m0 = (long)blockIdx.y * 128, n0 = (long)blockIdx.x * 128;
    const int nk = K >> 5;

    f32x4 acc[4][4];
    const f32x4 zero = {0.f, 0.f, 0.f, 0.f};
#pragma unroll
    for (int i = 0; i < 4; i++)
#pragma unroll
        for (int j = 0; j < 4; j++) acc[i][j] = zero;

    auto stage = [&](int buf, int kt) {
#pragma unroll
        for (int i = 0; i < 2; i++) {
            int o = (i * 256 + tid) * 16;
            int row = o >> 6;
            int cl = ((o >> 4) & 3) ^ ((row >> 1) & 3);
            gload_lds16(A + (m0 + row) * (long)K + kt * 32 + cl * 8,
                        (void*)&As[buf][(i * 256 + w * 64) * 8]);
        }
#pragma unroll
        for (int i = 0; i < 2; i++) {
            int o = (i * 256 + tid) * 16;
            int row = o >> 6;
            int cl = ((o >> 4) & 3) ^ ((row >> 1) & 3);
            gload_lds16(Bt + (n0 + row) * (long)K + kt * 32 + cl * 8,
                        (void*)&Bs[buf][(i * 256 + w * 64) * 8]);
        }
    };

    stage(0, 0);
    __syncthreads();
    int buf = 0;
    for (int kt = 0; kt < nk; ++kt) {
        if (kt + 1 < nk) stage(buf ^ 1, kt + 1);
        bf16x8 af[4], bf[4];
#pragma unroll
        for (int i = 0; i < 4; i++) {
            int rowa = wm * 64 + i * 16 + c;
            int cha = g ^ ((rowa >> 1) & 3);
            af[i] = *(const bf16x8*)&As[buf][rowa * 32 + cha * 8];
            int rowb = wn * 64 + i * 16 + c;
            int chb = g ^ ((rowb >> 1) & 3);
            bf[i] = *(const bf16x8*)&Bs[buf][rowb * 32 + chb * 8];
        }
#pragma unroll
        for (int i = 0; i < 4; i++)
#pragma unroll
            for (int j = 0; j < 4; j++) acc[i][j] = mfma32(af[i], bf[j], acc[i][j]);
        __syncthreads();
        buf ^= 1;
    }

#pragma unroll
    for (int i = 0; i < 4; i++)
#pragma unroll
        for (int j = 0; j < 4; j++) {
            long row0 = m0 + wm * 64 + i * 16 + g * 4;
            long col = n0 + wn * 64 + j * 16 + c;
#pragma unroll
            for (int r = 0; r < 4; r++) {
                float v = acc[i][j][r];
                if (OUT_BF16)
                    ((u16*)Cout)[(row0 + r) * (long)N + col] = f2bf(v);
                else
                    ((float*)Cout)[(row0 + r) * (long)N + col] = v;
            }
        }
}

// ---------------------------------------------------------------------------
// Flash sliding-window GQA, double-buffered (stage-first + 1 barrier/tile).
// Block: 512 thr = 8 waves; (q-tile of 128, h, b). Wave owns 16 q-rows.
#define ATT_SCALE 0.08838834764831845f
#define L2E 1.4426950408889634f

__global__ __launch_bounds__(512) void attn_kernel(const u16* QKV, const u16* Vt, u16* AO) {
    __shared__ u16 Ks[2][64 * 128];
    __shared__ u16 Vs[2][128 * 64];
    const int tid = threadIdx.x;
    const int w = tid >> 6, l = tid & 63, g = l >> 4, c = l & 15;
    const int h = blockIdx.y;
    const int b = blockIdx.z;
    const int kvh = h >> 2;
    const int q0 = blockIdx.x * 128;
    const int qb = q0 + w * 16;

    bf16x8 bq[4];
    {
        const u16* qrow = QKV + (long)(b * 2048 + qb + c) * 3072 + h * 128;
#pragma unroll
        for (int kc = 0; kc < 4; kc++) bq[kc] = *(const bf16x8*)(qrow + kc * 32 + g * 8);
    }

    f32x4 acc_o[8];
    const f32x4 zero = {0.f, 0.f, 0.f, 0.f};
#pragma unroll
    for (int i = 0; i < 8; i++) acc_o[i] = zero;
    float m_run = -3.0e38f, l_run = 0.f;

    const int t_lo = (q0 > 511) ? ((q0 - 511) >> 6) : 0;
    const int t_hi = (q0 + 127) >> 6;

    auto stage = [&](int sb, int t) {
        const int kv0 = t * 64;
#pragma unroll
        for (int i = 0; i < 2; i++) {
            int o = (i * 512 + tid) * 16;
            int key = o >> 8;
            int cl = ((o >> 4) & 15) ^ (key & 15);
            gload_lds16(QKV + (long)(b * 2048 + kv0 + key) * 3072 + 2048 + kvh * 128 + cl * 8,
                        (void*)&Ks[sb][(i * 512 + w * 64) * 8]);
        }
#pragma unroll
        for (int i = 0; i < 2; i++) {
            int o = (i * 512 + tid) * 16;
            int d = o >> 7;
            int cl = ((o >> 4) & 7) ^ (d & 7);
            gload_lds16(Vt + (long)((b * 4 + kvh) * 128 + d) * 2048 + kv0 + cl * 8,
                        (void*)&Vs[sb][(i * 512 + w * 64) * 8]);
        }
    };

    stage(0, t_lo);
    __syncthreads();
    int buf = 0;

    for (int t = t_lo; t <= t_hi; ++t) {
        const int kv0 = t * 64;
        if (t < t_hi) stage(buf ^ 1, t + 1);       // overlap with compute below

        const bool active = (kv0 <= qb + 15) && (kv0 + 63 >= qb - 511);
        if (active) {
            f32x4 sacc[4];
#pragma unroll
            for (int n = 0; n < 4; n++) {
                sacc[n] = zero;
#pragma unroll
                for (int kc = 0; kc < 4; kc++) {
                    int row = n * 16 + c;
                    int ch = (kc * 4 + g) ^ c;
                    bf16x8 kf = *(const bf16x8*)&Ks[buf][row * 128 + ch * 8];
                    sacc[n] = mfma32(kf, bq[kc], sacc[n]);
                }
            }

            const bool edge = (kv0 + 63 > qb) || (kv0 < qb + 15 - 511);
            float p[4][4];
            float m_tile = -3.0e38f;
#pragma unroll
            for (int n = 0; n < 4; n++)
#pragma unroll
                for (int r = 0; r < 4; r++) {
                    float s = sacc[n][r] * ATT_SCALE;
                    if (edge) {
                        int j = kv0 + n * 16 + 4 * g + r;
                        int q = qb + c;
                        if (j > q || j < q - 511) s = -__builtin_inff();
                    }
                    p[n][r] = s;
                    m_tile = fmaxf(m_tile, s);
                }
            m_tile = fmaxf(m_tile, __shfl_xor(m_tile, 16));
            m_tile = fmaxf(m_tile, __shfl_xor(m_tile, 32));
            float m_new = fmaxf(m_run, m_tile);
            float alpha = exp2f((m_run - m_new) * L2E);
            float lsum = 0.f;
#pragma unroll
            for (int n = 0; n < 4; n++)
#pragma unroll
                for (int r = 0; r < 4; r++) {
                    float e = exp2f((p[n][r] - m_new) * L2E);
                    p[n][r] = e;
                    lsum += e;
                }
            lsum += __shfl_xor(lsum, 16);
            lsum += __shfl_xor(lsum, 32);
            l_run = l_run * alpha + lsum;
            m_run = m_new;

            float alpha_r[4];
#pragma unroll
            for (int r = 0; r < 4; r++) alpha_r[r] = __shfl(alpha, (g << 4) + 4 * g + r);
#pragma unroll
            for (int dn = 0; dn < 8; dn++) {
                f32x4 t2 = acc_o[dn];
                t2[0] *= alpha_r[0]; t2[1] *= alpha_r[1];
                t2[2] *= alpha_r[2]; t2[3] *= alpha_r[3];
                acc_o[dn] = t2;
            }

            bf16x4 ap[4];
#pragma unroll
            for (int n = 0; n < 4; n++) {
                union { u16x4 u; bf16x4 b; } pk;
                pk.u[0] = f2bf(p[n][0]); pk.u[1] = f2bf(p[n][1]);
                pk.u[2] = f2bf(p[n][2]); pk.u[3] = f2bf(p[n][3]);
                ap[n] = pk.b;
            }

#pragma unroll
            for (int n = 0; n < 4; n++)
#pragma unroll
                for (int dn = 0; dn < 8; dn++) {
                    int row = dn * 16 + c;
                    int ch = (2 * n + (g >> 1)) ^ (c & 7);
                    bf16x4 vf = *(const bf16x4*)&Vs[buf][row * 64 + ch * 8 + (g & 1) * 4];
                    acc_o[dn] = mfma16(ap[n], vf, acc_o[dn]);
                }
        }
        __syncthreads();                            // drains stage(t+1) + reads
        buf ^= 1;
    }

    float lr[4];
#pragma unroll
    for (int r = 0; r < 4; r++) {
        float lq = __shfl(l_run, (g << 4) + 4 * g + r);
        lr[r] = 1.f / lq;
    }
#pragma unroll
    for (int dn = 0; dn < 8; dn++)
#pragma unroll
        for (int r = 0; r < 4; r++) {
            long row = (long)(b * 2048 + qb + 4 * g + r);
            AO[row * 2048 + h * 128 + dn * 16 + c] = f2bf(acc_o[dn][r] * lr[r]);
        }
}

// ---------------------------------------------------------------------------
extern "C" void kernel_launch(void* const* d_in, const int* in_sizes, int n_in,
                              void* d_out, int out_size, void* d_ws, size_t ws_size,
                              hipStream_t stream) {
    const float* x = (const float*)d_in[0];
    const float* wq = (const float*)d_in[1];
    const float* wk = (const float*)d_in[2];
    const float* wv = (const float*)d_in[3];
    const float* wo = (const float*)d_in[4];
    float* out = (float*)d_out;

    char* ws = (char*)d_ws;
    u16* xb = (u16*)(ws);                         // [4096][2048]        16.78 MB
    u16* wAll = (u16*)(ws + 16777216);            // [3072][2048] (BT)   12.58 MB
    u16* woT = (u16*)(ws + 29360128);             // [2048][2048] (BT)    8.39 MB
    u16* QKV = (u16*)(ws + 37748736);             // [4096][3072]        25.17 MB
    u16* Vt = (u16*)(ws + 62914560);              // [1024][2048]         4.19 MB
    u16* AO = (u16*)(ws + 67108864);              // [4096][2048]        16.78 MB
    float* ct = (float*)(ws + 83886080);          // [2048][64]
    float* st = (float*)(ws + 84410368);          // [2048][64]

    prep_kernel<<<18944, 256, 0, stream>>>(x, wq, wk, wv, wo, xb, wAll, woT, ct, st);

    // QKV = xb @ wAll^T
    gemm_bt_kernel<true><<<dim3(24, 32), 256, 0, stream>>>(xb, wAll, QKV, 4096, 3072, 2048);

    rope2_kernel<<<2560, 256, 0, stream>>>(QKV, ct, st);

    // V columns of QKV -> Vt [b*512+d][s]
    transpose_bf16_kernel<<<dim3(16, 64, 2), 256, 0, stream>>>(
        QKV + 2560, 3072, (long)2048 * 3072, Vt, 2048, (long)512 * 2048);

    attn_kernel<<<dim3(16, 16, 2), 512, 0, stream>>>(QKV, Vt, AO);

    // out = AO @ woT^T
    gemm_bt_kernel<false><<<dim3(16, 32), 256, 0, stream>>>(AO, woT, out, 4096, 2048, 2048);
}

// Round 9
// 178.108 us; speedup vs baseline: 1.1726x; 1.0224x over previous
//
#include <hip/hip_runtime.h>
#include <math.h>

// ---------------------------------------------------------------------------
// SlidingWindowGQA: x[2,2048,2048] f32, wq[2048,2048], wk/wv[2048,512], wo[2048,2048]
// out f32 [2,2048,2048].  B=2 S=2048 H=16 KVH=4 D=128 WINDOW=512.
// R9: R8 base (proven 72-VGPR GEMM) + Q-RoPE fused into attn's register load,
//     K-rope+V-transpose merged into one launch, T13 defer-max in softmax.
// ---------------------------------------------------------------------------

typedef unsigned short u16;
typedef __attribute__((ext_vector_type(4))) float f32x4;
typedef __attribute__((ext_vector_type(8))) __bf16 bf16x8;
typedef __attribute__((ext_vector_type(4))) __bf16 bf16x4;
typedef __attribute__((ext_vector_type(4))) short s16x4;
typedef __attribute__((ext_vector_type(8))) unsigned short u16x8;
typedef __attribute__((ext_vector_type(4))) unsigned short u16x4;

#define DEV static __device__ __forceinline__

DEV float bf2f(u16 h) {
    union { unsigned int i; float f; } x;
    x.i = ((unsigned int)h) << 16;
    return x.f;
}
DEV u16 f2bf(float f) {
    union { float f; unsigned int i; } x;
    x.f = f;
    unsigned int u = x.i;
    return (u16)((u + 0x7FFFu + ((u >> 16) & 1u)) >> 16);
}

DEV f32x4 mfma32(bf16x8 a, bf16x8 b, f32x4 c) {
    return __builtin_amdgcn_mfma_f32_16x16x32_bf16(a, b, c, 0, 0, 0);
}
DEV f32x4 mfma16(bf16x4 a, bf16x4 b, f32x4 c) {
#if __has_builtin(__builtin_amdgcn_mfma_f32_16x16x16_bf16)
    return __builtin_amdgcn_mfma_f32_16x16x16_bf16(a, b, c, 0, 0, 0);
#else
    union { bf16x4 v; s16x4 s; } ua, ub;
    ua.v = a; ub.v = b;
    return __builtin_amdgcn_mfma_f32_16x16x16bf16_1k(ua.s, ub.s, c, 0, 0, 0);
#endif
}

DEV void gload_lds16(const void* g, void* lds) {
    __builtin_amdgcn_global_load_lds(
        (const __attribute__((address_space(1))) unsigned int*)g,
        (__attribute__((address_space(3))) unsigned int*)lds, 16, 0, 0);
}

// ---------------------------------------------------------------------------
// Fused prep: sincos table + x->bf16 cast + 4x weight convert/transpose.
__global__ __launch_bounds__(256) void prep_kernel(const float* x, const float* wq,
                                                   const float* wk, const float* wv,
                                                   const float* wo, u16* xb, u16* wAll,
                                                   u16* woT, float* ct, float* st) {
    __shared__ float tile[32][33];
    const int bid = blockIdx.x;
    const int tid = threadIdx.x;
    if (bid < 512) {
        int idx = bid * 256 + tid;                 // 131072
        int s = idx >> 6, d = idx & 63;
        float inv = exp2f(-(float)d * (13.287712379549449f / 64.f));
        float a = (float)s * inv;
        float sv, cv;
        sincosf(a, &sv, &cv);
        ct[idx] = cv;
        st[idx] = sv;
        return;
    }
    if (bid < 8704) {
        int i = (bid - 512) * 256 + tid;           // 2097152 float4s
        float4 v = ((const float4*)x)[i];
        u16x4 o;
        o[0] = f2bf(v.x); o[1] = f2bf(v.y); o[2] = f2bf(v.z); o[3] = f2bf(v.w);
        ((u16x4*)xb)[i] = o;
        return;
    }
    // convT: f32 [R][C](ldi) -> bf16 [C][R](ld 2048)
    int r = bid - 8704;
    const float* in;
    u16* out;
    int ldi, bx, by;
    if (r < 4096) { in = wq; out = wAll; ldi = 2048; bx = r & 63; by = r >> 6; }
    else if (r < 5120) { r -= 4096; in = wk; out = wAll + (long)2048 * 2048; ldi = 512; bx = r & 15; by = r >> 4; }
    else if (r < 6144) { r -= 5120; in = wv; out = wAll + (long)2560 * 2048; ldi = 512; bx = r & 15; by = r >> 4; }
    else { r -= 6144; in = wo; out = woT; ldi = 2048; bx = r & 63; by = r >> 6; }
    int cc = tid & 31, rb = tid >> 5;
    long r0 = (long)by * 32, c0 = (long)bx * 32;
#pragma unroll
    for (int i = 0; i < 4; i++)
        tile[rb + i * 8][cc] = in[(r0 + rb + i * 8) * (long)ldi + c0 + cc];
    __syncthreads();
#pragma unroll
    for (int i = 0; i < 4; i++)
        out[(c0 + rb + i * 8) * 2048L + r0 + cc] = f2bf(tile[cc][rb + i * 8]);
}

// Merged K-RoPE + V-transpose (Q-rope moved into attn).
//   [0,512):    K-rope on QKV cols [2048,2560): 4096 rows x 4 heads x 8 chunks
//   [512,2560): V cols of QKV -> Vt [b*512+d][s]  (32x32 tile transpose)
__global__ __launch_bounds__(256) void ropeKT_kernel(u16* QKV, u16* Vt,
                                                     const float* ct, const float* st) {
    __shared__ u16 tile[32][33];
    const int bid = blockIdx.x;
    const int tid = threadIdx.x;
    if (bid < 512) {
        int idx = bid * 256 + tid;                 // 131072
        int m = idx >> 5;
        int rest = idx & 31;
        int hoff = 2048 + (rest >> 3) * 128;
        int d0 = (rest & 7) * 8;
        int s = m & 2047;
        u16* p1 = QKV + (long)m * 3072 + hoff + d0;
        u16* p2 = p1 + 64;
        u16x8 v1 = *(const u16x8*)p1;
        u16x8 v2 = *(const u16x8*)p2;
        const float* cp = ct + s * 64 + d0;
        const float* sp = st + s * 64 + d0;
        u16x8 o1, o2;
#pragma unroll
        for (int j = 0; j < 8; j++) {
            float x1 = bf2f(v1[j]), x2 = bf2f(v2[j]);
            float cc = cp[j], ss = sp[j];
            o1[j] = f2bf(x1 * cc - x2 * ss);
            o2[j] = f2bf(x2 * cc + x1 * ss);
        }
        *(u16x8*)p1 = o1;
        *(u16x8*)p2 = o2;
        return;
    }
    int r = bid - 512;                             // 2048 transpose blocks
    int z = r >> 10;
    int rr = r & 1023;
    int bx = rr & 15, by = rr >> 4;                // bx<16 (V cols), by<64 (rows)
    const u16* in = QKV + 2560 + (long)z * 2048 * 3072;
    u16* out = Vt + (long)z * 512 * 2048;
    int cc = tid & 31, rb = tid >> 5;
    long r0 = (long)by * 32, c0 = (long)bx * 32;
#pragma unroll
    for (int i = 0; i < 4; i++)
        tile[rb + i * 8][cc] = in[(r0 + rb + i * 8) * 3072 + c0 + cc];
    __syncthreads();
#pragma unroll
    for (int i = 0; i < 4; i++)
        out[(c0 + rb + i * 8) * 2048L + r0 + cc] = tile[cc][rb + i * 8];
}

// ---------------------------------------------------------------------------
// GEMM (R1/R8 proven, untouched): C = A[M][K] * Bt[N][K]^T, 128x128 tile, BK=32.
template <bool OUT_BF16>
__global__ __launch_bounds__(256) void gemm_bt_kernel(const u16* A, const u16* Bt, void* Cout,
                                                      int M, int N, int K) {
    __shared__ u16 As[2][128 * 32];
    __shared__ u16 Bs[2][128 * 32];
    const int tid = threadIdx.x;
    const int w = tid >> 6, l = tid & 63, g = l >> 4, c = l & 15;
    const int wm = w >> 1, wn = w & 1;
    const long m0 = (long)blockIdx.y * 128, n0 = (long)blockIdx.x * 128;
    const int nk = K >> 5;

    f32x4 acc[4][4];
    const f32x4 zero = {0.f, 0.f, 0.f, 0.f};
#pragma unroll
    for (int i = 0; i < 4; i++)
#pragma unroll
        for (int j = 0; j < 4; j++) acc[i][j] = zero;

    auto stage = [&](int buf, int kt) {
#pragma unroll
        for (int i = 0; i < 2; i++) {
            int o = (i * 256 + tid) * 16;
            int row = o >> 6;
            int cl = ((o >> 4) & 3) ^ ((row >> 1) & 3);
            gload_lds16(A + (m0 + row) * (long)K + kt * 32 + cl * 8,
                        (void*)&As[buf][(i * 256 + w * 64) * 8]);
        }
#pragma unroll
        for (int i = 0; i < 2; i++) {
            int o = (i * 256 + tid) * 16;
            int row = o >> 6;
            int cl = ((o >> 4) & 3) ^ ((row >> 1) & 3);
            gload_lds16(Bt + (n0 + row) * (long)K + kt * 32 + cl * 8,
                        (void*)&Bs[buf][(i * 256 + w * 64) * 8]);
        }
    };

    stage(0, 0);
    __syncthreads();
    int buf = 0;
    for (int kt = 0; kt < nk; ++kt) {
        if (kt + 1 < nk) stage(buf ^ 1, kt + 1);
        bf16x8 af[4], bf[4];
#pragma unroll
        for (int i = 0; i < 4; i++) {
            int rowa = wm * 64 + i * 16 + c;
            int cha = g ^ ((rowa >> 1) & 3);
            af[i] = *(const bf16x8*)&As[buf][rowa * 32 + cha * 8];
            int rowb = wn * 64 + i * 16 + c;
            int chb = g ^ ((rowb >> 1) & 3);
            bf[i] = *(const bf16x8*)&Bs[buf][rowb * 32 + chb * 8];
        }
#pragma unroll
        for (int i = 0; i < 4; i++)
#pragma unroll
            for (int j = 0; j < 4; j++) acc[i][j] = mfma32(af[i], bf[j], acc[i][j]);
        __syncthreads();
        buf ^= 1;
    }

#pragma unroll
    for (int i = 0; i < 4; i++)
#pragma unroll
        for (int j = 0; j < 4; j++) {
            long row0 = m0 + wm * 64 + i * 16 + g * 4;
            long col = n0 + wn * 64 + j * 16 + c;
#pragma unroll
            for (int r = 0; r < 4; r++) {
                float v = acc[i][j][r];
                if (OUT_BF16)
                    ((u16*)Cout)[(row0 + r) * (long)N + col] = f2bf(v);
                else
                    ((float*)Cout)[(row0 + r) * (long)N + col] = v;
            }
        }
}

// ---------------------------------------------------------------------------
// Flash sliding-window GQA, double-buffered; Q-RoPE applied in registers;
// T13 defer-max (skip O-rescale when all q-rows' tile max is within 8 of m_run).
#define ATT_SCALE 0.08838834764831845f
#define L2E 1.4426950408889634f

__global__ __launch_bounds__(512) void attn_kernel(const u16* QKV, const u16* Vt, u16* AO,
                                                   const float* ct, const float* st) {
    __shared__ u16 Ks[2][64 * 128];
    __shared__ u16 Vs[2][128 * 64];
    const int tid = threadIdx.x;
    const int w = tid >> 6, l = tid & 63, g = l >> 4, c = l & 15;
    const int h = blockIdx.y;
    const int b = blockIdx.z;
    const int kvh = h >> 2;
    const int q0 = blockIdx.x * 128;
    const int qb = q0 + w * 16;

    bf16x8 bq[4];
    {
        const u16* qrow = QKV + (long)(b * 2048 + qb + c) * 3072 + h * 128;
#pragma unroll
        for (int kc = 0; kc < 4; kc++) bq[kc] = *(const bf16x8*)(qrow + kc * 32 + g * 8);
        // In-register RoPE on Q: dim d = kc*32 + g*8 + j; pairs (d, d+64) =
        // (bq[kc], bq[kc+2]) elementwise for kc in {0,1}; cos/sin index d&63.
        const float* cb = ct + (qb + c) * 64 + g * 8;
        const float* sb = st + (qb + c) * 64 + g * 8;
#pragma unroll
        for (int kc = 0; kc < 2; kc++) {
            union { bf16x8 v; u16x8 u; } lo, hi;
            lo.v = bq[kc]; hi.v = bq[kc + 2];
#pragma unroll
            for (int j = 0; j < 8; j++) {
                float x1 = bf2f(lo.u[j]), x2 = bf2f(hi.u[j]);
                float cc = cb[kc * 32 + j], ss = sb[kc * 32 + j];
                lo.u[j] = f2bf(x1 * cc - x2 * ss);
                hi.u[j] = f2bf(x2 * cc + x1 * ss);
            }
            bq[kc] = lo.v; bq[kc + 2] = hi.v;
        }
    }

    f32x4 acc_o[8];
    const f32x4 zero = {0.f, 0.f, 0.f, 0.f};
#pragma unroll
    for (int i = 0; i < 8; i++) acc_o[i] = zero;
    float m_run = -3.0e38f, l_run = 0.f;

    const int t_lo = (q0 > 511) ? ((q0 - 511) >> 6) : 0;
    const int t_hi = (q0 + 127) >> 6;

    auto stage = [&](int sb_, int t) {
        const int kv0 = t * 64;
#pragma unroll
        for (int i = 0; i < 2; i++) {
            int o = (i * 512 + tid) * 16;
            int key = o >> 8;
            int cl = ((o >> 4) & 15) ^ (key & 15);
            gload_lds16(QKV + (long)(b * 2048 + kv0 + key) * 3072 + 2048 + kvh * 128 + cl * 8,
                        (void*)&Ks[sb_][(i * 512 + w * 64) * 8]);
        }
#pragma unroll
        for (int i = 0; i < 2; i++) {
            int o = (i * 512 + tid) * 16;
            int d = o >> 7;
            int cl = ((o >> 4) & 7) ^ (d & 7);
            gload_lds16(Vt + (long)((b * 4 + kvh) * 128 + d) * 2048 + kv0 + cl * 8,
                        (void*)&Vs[sb_][(i * 512 + w * 64) * 8]);
        }
    };

    stage(0, t_lo);
    __syncthreads();
    int buf = 0;

    for (int t = t_lo; t <= t_hi; ++t) {
        const int kv0 = t * 64;
        if (t < t_hi) stage(buf ^ 1, t + 1);       // overlap with compute below

        const bool active = (kv0 <= qb + 15) && (kv0 + 63 >= qb - 511);
        if (active) {
            f32x4 sacc[4];
#pragma unroll
            for (int n = 0; n < 4; n++) {
                sacc[n] = zero;
#pragma unroll
                for (int kc = 0; kc < 4; kc++) {
                    int row = n * 16 + c;
                    int ch = (kc * 4 + g) ^ c;
                    bf16x8 kf = *(const bf16x8*)&Ks[buf][row * 128 + ch * 8];
                    sacc[n] = mfma32(kf, bq[kc], sacc[n]);
                }
            }

            const bool edge = (kv0 + 63 > qb) || (kv0 < qb + 15 - 511);
            float p[4][4];
            float m_tile = -3.0e38f;
#pragma unroll
            for (int n = 0; n < 4; n++)
#pragma unroll
                for (int r = 0; r < 4; r++) {
                    float s = sacc[n][r] * ATT_SCALE;
                    if (edge) {
                        int j = kv0 + n * 16 + 4 * g + r;
                        int q = qb + c;
                        if (j > q || j < q - 511) s = -__builtin_inff();
                    }
                    p[n][r] = s;
                    m_tile = fmaxf(m_tile, s);
                }
            m_tile = fmaxf(m_tile, __shfl_xor(m_tile, 16));
            m_tile = fmaxf(m_tile, __shfl_xor(m_tile, 32));

            // T13 defer-max: skip max-update + O-rescale while bounded (P <= e^8).
            const bool keep = __all(m_tile - m_run <= 8.f);
            const float m_new = keep ? m_run : fmaxf(m_run, m_tile);

            float lsum = 0.f;
#pragma unroll
            for (int n = 0; n < 4; n++)
#pragma unroll
                for (int r = 0; r < 4; r++) {
                    float e = exp2f((p[n][r] - m_new) * L2E);
                    p[n][r] = e;
                    lsum += e;
                }
            lsum += __shfl_xor(lsum, 16);
            lsum += __shfl_xor(lsum, 32);

            if (!keep) {
                float alpha = exp2f((m_run - m_new) * L2E);
                l_run = l_run * alpha + lsum;
                m_run = m_new;
                float alpha_r[4];
#pragma unroll
                for (int r = 0; r < 4; r++) alpha_r[r] = __shfl(alpha, (g << 4) + 4 * g + r);
#pragma unroll
                for (int dn = 0; dn < 8; dn++) {
                    f32x4 t2 = acc_o[dn];
                    t2[0] *= alpha_r[0]; t2[1] *= alpha_r[1];
                    t2[2] *= alpha_r[2]; t2[3] *= alpha_r[3];
                    acc_o[dn] = t2;
                }
            } else {
                l_run += lsum;
            }

            bf16x4 ap[4];
#pragma unroll
            for (int n = 0; n < 4; n++) {
                union { u16x4 u; bf16x4 b; } pk;
                pk.u[0] = f2bf(p[n][0]); pk.u[1] = f2bf(p[n][1]);
                pk.u[2] = f2bf(p[n][2]); pk.u[3] = f2bf(p[n][3]);
                ap[n] = pk.b;
            }

#pragma unroll
            for (int n = 0; n < 4; n++)
#pragma unroll
                for (int dn = 0; dn < 8; dn++) {
                    int row = dn * 16 + c;
                    int ch = (2 * n + (g >> 1)) ^ (c & 7);
                    bf16x4 vf = *(const bf16x4*)&Vs[buf][row * 64 + ch * 8 + (g & 1) * 4];
                    acc_o[dn] = mfma16(ap[n], vf, acc_o[dn]);
                }
        }
        __syncthreads();                            // drains stage(t+1) + reads
        buf ^= 1;
    }

    float lr[4];
#pragma unroll
    for (int r = 0; r < 4; r++) {
        float lq = __shfl(l_run, (g << 4) + 4 * g + r);
        lr[r] = 1.f / lq;
    }
#pragma unroll
    for (int dn = 0; dn < 8; dn++)
#pragma unroll
        for (int r = 0; r < 4; r++) {
            long row = (long)(b * 2048 + qb + 4 * g + r);
            AO[row * 2048 + h * 128 + dn * 16 + c] = f2bf(acc_o[dn][r] * lr[r]);
        }
}

// ---------------------------------------------------------------------------
extern "C" void kernel_launch(void* const* d_in, const int* in_sizes, int n_in,
                              void* d_out, int out_size, void* d_ws, size_t ws_size,
                              hipStream_t stream) {
    const float* x = (const float*)d_in[0];
    const float* wq = (const float*)d_in[1];
    const float* wk = (const float*)d_in[2];
    const float* wv = (const float*)d_in[3];
    const float* wo = (const float*)d_in[4];
    float* out = (float*)d_out;

    char* ws = (char*)d_ws;
    u16* xb = (u16*)(ws);                         // [4096][2048]        16.78 MB
    u16* wAll = (u16*)(ws + 16777216);            // [3072][2048] (BT)   12.58 MB
    u16* woT = (u16*)(ws + 29360128);             // [2048][2048] (BT)    8.39 MB
    u16* QKV = (u16*)(ws + 37748736);             // [4096][3072]        25.17 MB
    u16* Vt = (u16*)(ws + 62914560);              // [1024][2048]         4.19 MB
    u16* AO = (u16*)(ws + 67108864);              // [4096][2048]        16.78 MB
    float* ct = (float*)(ws + 83886080);          // [2048][64]
    float* st = (float*)(ws + 84410368);          // [2048][64]

    prep_kernel<<<18944, 256, 0, stream>>>(x, wq, wk, wv, wo, xb, wAll, woT, ct, st);

    // QKV = xb @ wAll^T (Q raw; K gets rope below; Q rope applied inside attn)
    gemm_bt_kernel<true><<<dim3(24, 32), 256, 0, stream>>>(xb, wAll, QKV, 4096, 3072, 2048);

    // K-rope + V-transpose in one launch
    ropeKT_kernel<<<2560, 256, 0, stream>>>(QKV, Vt, ct, st);

    attn_kernel<<<dim3(16, 16, 2), 512, 0, stream>>>(QKV, Vt, AO, ct, st);

    // out = AO @ woT^T
    gemm_bt_kernel<false><<<dim3(16, 32), 256, 0, stream>>>(AO, woT, out, 4096, 2048, 2048);
}